// Round 4
// baseline (1770.403 us; speedup 1.0000x reference)
//
#include <hip/hip_runtime.h>
#include <hip/hip_bf16.h>

// GATFusionBlockPosOnly: B=8, N=1024, D=256, 8 GAT heads, 4 CA heads.
// Round 4: I/O dtype corrected to FP32 (reference is float32; the "(bf16" in
// the harness error label is hardcoded text, not a dtype signal).
// Internal: fp32 for threshold-critical paths (sim y, adjacency fa, Who
// accumulator, softmax stats); bf16 workspace tiles for smooth intermediates.
// Workspace layout (22 MB):
//   [0,410KB)    fp32 smalls: pq,cnt,sq,s1,s2,rmx,rin,cam,civ
//   [512KB,1.5MB) conn bitmask   [1600KB] sel8 (8KB)
//   [2MB,10MB)   S0 fp32: y -> fa -> Who ; then (bf16) vb
//   [10MB,14MB)  T0 bf16: Wh -> kv -> Ob
//   [14MB,18MB)  T1 bf16: ht -> qx -> kb
//   [18MB,22MB)  T2 bf16: gout -> qb

#define BB 8
#define NN 1024
#define DD 256
#define HG 8
#define HC 4
#define BN (BB*NN)

typedef __hip_bfloat16 bf16;

__device__ __forceinline__ float4 ld4bf(const bf16* p){
  uint2 u = *(const uint2*)p;
  float4 r;
  r.x=__uint_as_float(u.x<<16); r.y=__uint_as_float(u.x&0xffff0000u);
  r.z=__uint_as_float(u.y<<16); r.w=__uint_as_float(u.y&0xffff0000u);
  return r;
}
__device__ __forceinline__ void load8(const bf16* p, float* v){
  uint4 u=*(const uint4*)p;
  v[0]=__uint_as_float(u.x<<16); v[1]=__uint_as_float(u.x&0xffff0000u);
  v[2]=__uint_as_float(u.y<<16); v[3]=__uint_as_float(u.y&0xffff0000u);
  v[4]=__uint_as_float(u.z<<16); v[5]=__uint_as_float(u.z&0xffff0000u);
  v[6]=__uint_as_float(u.w<<16); v[7]=__uint_as_float(u.w&0xffff0000u);
}
__device__ __forceinline__ void load8(const float* p, float* v){
  float4 a=*(const float4*)p, b=*(const float4*)(p+4);
  v[0]=a.x;v[1]=a.y;v[2]=a.z;v[3]=a.w;v[4]=b.x;v[5]=b.y;v[6]=b.z;v[7]=b.w;
}
__device__ __forceinline__ void st4bf(bf16* p, float a, float b, float c, float d){
  union{ bf16 h[4]; uint2 u; } pk;
  pk.h[0]=__float2bfloat16(a); pk.h[1]=__float2bfloat16(b);
  pk.h[2]=__float2bfloat16(c); pk.h[3]=__float2bfloat16(d);
  *(uint2*)p = pk.u;
}
__device__ __forceinline__ float wredsum(float v){
  #pragma unroll
  for(int o=32;o>0;o>>=1) v += __shfl_xor(v,o);
  return v;
}
__device__ __forceinline__ float wredmax(float v){
  #pragma unroll
  for(int o=32;o>0;o>>=1) v = fmaxf(v,__shfl_xor(v,o));
  return v;
}
__device__ __forceinline__ float eluf(float x){ return x>0.f ? x : expm1f(x); }
__device__ __forceinline__ float leakyf(float z){ return z>=0.f ? z : 0.2f*z; }
__device__ __forceinline__ float exp0(float a){ return expf(fminf(a, 0.f)); } // args provably <=0
__device__ __forceinline__ float flushf(float v){ return (fabsf(v) < 1.0e30f) ? v : 0.f; }

// ---------- pos_query partial sums (atomic) ----------
__global__ __launch_bounds__(256) void k_posq(const float* __restrict__ x, const int* __restrict__ mask,
                                              float* __restrict__ pq, float* __restrict__ cnt){
  int b = blockIdx.x, chunk = blockIdx.y;   // grid (BB,16)
  int d = threadIdx.x;
  int n0 = chunk*64;
  float acc = 0.f; float c = 0.f;
  for (int i=0;i<64;i++){
    int n = n0+i;
    if (mask[b*NN+n]==1){ acc += x[((size_t)(b*NN+n))*DD + d]; c += 1.f; }
  }
  atomicAdd(&pq[b*DD+d], acc);
  if (d==0) atomicAdd(&cnt[b], c);
}

// ---------- sq[b,e] = sum_d (pq[d]/cnt) * Wq[d,e] ----------
__global__ __launch_bounds__(256) void k_sq(const float* __restrict__ pq, const float* __restrict__ cnt,
                                            const float* __restrict__ Wq, float* __restrict__ sq){
  int b = blockIdx.x, e = threadIdx.x;
  float inv = 1.f / fmaxf(cnt[b], 1.f);
  float acc=0.f;
  for (int d0=0; d0<DD; d0++) acc += (pq[b*DD+d0]*inv) * Wq[d0*DD+e];
  sq[b*DD+e] = acc;
}

// ---------- pos_sim & sel ----------
__global__ __launch_bounds__(256) void k_simsel(const float* __restrict__ y, const float* __restrict__ sq,
                                                float* __restrict__ simOut, unsigned char* __restrict__ sel8){
  int r = blockIdx.x*4 + (threadIdx.x>>6);
  int lane = threadIdx.x & 63;
  int b = r>>10;
  float4 yv = *(const float4*)(y + (size_t)r*DD + lane*4);
  float4 qv = *(const float4*)(sq + b*DD + lane*4);
  float p = yv.x*qv.x + yv.y*qv.y + yv.z*qv.z + yv.w*qv.w;
  p = wredsum(p);
  if (lane==0){
    float s = p * 0.0625f;                       // 1/sqrt(256)
    float sim = 1.f/(1.f+expf(-s));
    simOut[r] = sim;
    sel8[r] = (sim > 0.97f) ? 1 : 0;
  }
}

// ---------- generic GEMM: C[8192,256] = A[8192,256] @ Bw[256,256] (Bw fp32) ----------
// EPI: 0 = store fp32, 1 = accumulate fp32, 2 = out_f32 = Xres + gamma*acc (flushed), 3 = store bf16
template<typename AT, int EPI>
__global__ __launch_bounds__(256) void k_gemm(const AT* __restrict__ A, const float* __restrict__ Bw,
    float* __restrict__ C, const float* __restrict__ Xres, const float* __restrict__ gamma,
    bf16* __restrict__ Obf){
  __shared__ float As[32][68];
  __shared__ float Bs[32][64];
  int tid = threadIdx.x;
  int tx = tid & 15, ty = tid >> 4;
  int colBase = blockIdx.x*64, rowBase = blockIdx.y*64;
  float acc[4][4] = {};
  for (int k0=0;k0<DD;k0+=32){
    {
      int r = tid>>2, kc = (tid&3)*8;
      float v[8]; load8(A + (size_t)(rowBase+r)*DD + k0+kc, v);
      #pragma unroll
      for (int i=0;i<8;i++) As[kc+i][r]=v[i];
    }
    {
      int kr = tid>>3, cc = (tid&7)*8;
      float v[8]; load8(Bw + (size_t)(k0+kr)*DD + colBase+cc, v);
      #pragma unroll
      for (int i=0;i<8;i++) Bs[kr][cc+i]=v[i];
    }
    __syncthreads();
    #pragma unroll
    for (int kk=0;kk<32;kk++){
      float4 a = *(const float4*)&As[kk][ty*4];
      float4 b = *(const float4*)&Bs[kk][tx*4];
      float av[4]={a.x,a.y,a.z,a.w}, bv[4]={b.x,b.y,b.z,b.w};
      #pragma unroll
      for (int i=0;i<4;i++)
        #pragma unroll
        for (int j=0;j<4;j++) acc[i][j] += av[i]*bv[j];
    }
    __syncthreads();
  }
  #pragma unroll
  for (int i=0;i<4;i++){
    size_t off = (size_t)(rowBase+ty*4+i)*DD + colBase + tx*4;
    if constexpr (EPI==0){
      *(float4*)(C+off) = make_float4(acc[i][0],acc[i][1],acc[i][2],acc[i][3]);
    } else if constexpr (EPI==1){
      float4 c = *(const float4*)(C+off);
      c.x+=acc[i][0]; c.y+=acc[i][1]; c.z+=acc[i][2]; c.w+=acc[i][3];
      *(float4*)(C+off)=c;
    } else if constexpr (EPI==2){
      float4 xr = *(const float4*)(Xres+off);
      float4 g  = *(const float4*)(gamma + colBase + tx*4);
      *(float4*)(C+off) = make_float4(
        flushf(xr.x + g.x*acc[i][0]), flushf(xr.y + g.y*acc[i][1]),
        flushf(xr.z + g.z*acc[i][2]), flushf(xr.w + g.w*acc[i][3]));
    } else {
      st4bf(Obf+off, acc[i][0], acc[i][1], acc[i][2], acc[i][3]);
    }
  }
}

// ---------- connectivity bitmask: conn[(b*N+n)*32 + m/32] ----------
__global__ __launch_bounds__(256) void k_connect(const float* __restrict__ fa, const unsigned char* __restrict__ sel8,
                                                 unsigned int* __restrict__ conn){
  __shared__ float As[32][68];
  __shared__ float Bs2[32][68];
  __shared__ unsigned char sg[64][64];
  int tid=threadIdx.x, tx=tid&15, ty=tid>>4;
  int b = blockIdx.z;
  int mBase = blockIdx.x*64, nBase = blockIdx.y*64;
  const float* fab = fa + (size_t)b*NN*DD;
  float acc[4][4]={};
  for (int k0=0;k0<DD;k0+=32){
    int r=tid>>2, kc=(tid&3)*8;
    { float v[8]; load8(fab + (size_t)(nBase+r)*DD + k0+kc, v);
      #pragma unroll
      for (int i=0;i<8;i++) As[kc+i][r]=v[i]; }
    { float v[8]; load8(fab + (size_t)(mBase+r)*DD + k0+kc, v);
      #pragma unroll
      for (int i=0;i<8;i++) Bs2[kc+i][r]=v[i]; }
    __syncthreads();
    #pragma unroll
    for (int kk=0;kk<32;kk++){
      float4 a=*(const float4*)&As[kk][ty*4];
      float4 bv=*(const float4*)&Bs2[kk][tx*4];
      float av[4]={a.x,a.y,a.z,a.w}, bb[4]={bv.x,bv.y,bv.z,bv.w};
      #pragma unroll
      for (int i=0;i<4;i++)
        #pragma unroll
        for (int j=0;j<4;j++) acc[i][j] += av[i]*bb[j];
    }
    __syncthreads();
  }
  #pragma unroll
  for (int i=0;i<4;i++)
    #pragma unroll
    for (int j=0;j<4;j++) sg[ty*4+i][tx*4+j] = acc[i][j] > 0.f;
  __syncthreads();
  if (tid<128){
    int row=tid>>1, w=tid&1;
    int nG = nBase+row;
    unsigned int word=0;
    if (sel8[b*NN + nG]){
      for (int j=0;j<32;j++){
        int m = mBase + w*32 + j;
        if (sg[row][w*32+j] && sel8[b*NN+m]) word |= (1u<<j);
      }
    }
    conn[((size_t)b*NN + nG)*32 + (mBase>>5) + w] = word;
  }
}

// ---------- s1/s2 = V @ a1, V @ a2 (wave per row); a1/a2 fp32 ----------
template<typename VT>
__global__ __launch_bounds__(256) void k_s1s2(const VT* __restrict__ V, const float* __restrict__ a1,
                                              const float* __restrict__ a2, float* __restrict__ s1, float* __restrict__ s2){
  int r = blockIdx.x*4 + (threadIdx.x>>6);
  int lane = threadIdx.x&63;
  float4 v;
  if constexpr (sizeof(VT)==2) v = ld4bf((const bf16*)V + (size_t)r*DD + lane*4);
  else                         v = *(const float4*)((const float*)V + (size_t)r*DD + lane*4);
  float4 w1 = *(const float4*)(a1+lane*4), w2 = *(const float4*)(a2+lane*4);
  float d1 = v.x*w1.x+v.y*w1.y+v.z*w1.z+v.w*w1.w;
  float d2 = v.x*w2.x+v.y*w2.y+v.z*w2.z+v.w*w2.w;
  d1=wredsum(d1); d2=wredsum(d2);
  if (lane==0){ s1[r]=d1; s2[r]=d2; }
}

// ---------- GAT row softmax stats (max & 1/sum) ----------
__global__ __launch_bounds__(256) void k_rowstats(const float* __restrict__ s1, const float* __restrict__ s2,
    const unsigned int* __restrict__ conn, float* __restrict__ rmax, float* __restrict__ rinv){
  int r = blockIdx.x*4 + (threadIdx.x>>6);
  int lane = threadIdx.x&63;
  int b = r>>10;
  float sr = s1[r];
  float e[16];
  float mx = -3.0e38f;
  #pragma unroll
  for (int t=0;t<16;t++){
    int m = lane + t*64;
    unsigned int w = conn[(size_t)r*32 + (m>>5)];
    float ev;
    if ((w>>(m&31))&1u){ ev = leakyf(sr + s2[b*NN+m]); }
    else ev = -9.0e15f;
    e[t]=ev; mx = fmaxf(mx,ev);
  }
  mx = wredmax(mx);
  float sm=0.f;
  #pragma unroll
  for (int t=0;t<16;t++) sm += exp0(e[t]-mx);
  sm = wredsum(sm);
  if (lane==0){ rmax[r]=mx; rinv[r]=1.f/sm; }
}

// ---------- fused GAT: Out(bf16) = elu(softmax(E) @ V) ----------
template<typename VT>
__global__ __launch_bounds__(256) void k_attn_av(const float* __restrict__ s1, const float* __restrict__ s2,
    const float* __restrict__ rmax, const float* __restrict__ rinv,
    const unsigned int* __restrict__ conn, const VT* __restrict__ V, bf16* __restrict__ Out){
  __shared__ float Ps[32][68];
  __shared__ float Vs[32][64];
  int tid=threadIdx.x, tx=tid&15, ty=tid>>4;
  int colBase = blockIdx.x*64, rowBase = blockIdx.y*64;
  int b = rowBase>>10;
  size_t bOff = (size_t)b*NN;
  int rB2 = tid>>5;   // 0..7
  float s1r[8], rmx8[8], rin8[8];
  #pragma unroll
  for (int i=0;i<8;i++){
    int rG = rowBase + i*8 + rB2;
    s1r[i]=s1[rG]; rmx8[i]=rmax[rG]; rin8[i]=rinv[rG];
  }
  int mm = tid&31;
  float acc[4][4]={};
  for (int k0=0;k0<NN;k0+=32){
    float s2v = s2[bOff + k0 + mm];
    #pragma unroll
    for (int i=0;i<8;i++){
      int row = i*8 + rB2;
      int rG = rowBase + row;
      unsigned int w = conn[(size_t)rG*32 + (k0>>5)];
      float ev = ((w>>mm)&1u) ? leakyf(s1r[i] + s2v) : -9.0e15f;
      Ps[mm][row] = exp0(ev - rmx8[i])*rin8[i];
    }
    {
      int kr=tid>>3, cc=(tid&7)*8;
      float v[8]; load8(V + (bOff + k0 + kr)*DD + colBase + cc, v);
      #pragma unroll
      for (int i=0;i<8;i++) Vs[kr][cc+i]=v[i];
    }
    __syncthreads();
    #pragma unroll
    for (int kk=0;kk<32;kk++){
      float4 a=*(const float4*)&Ps[kk][ty*4];
      float4 bv=*(const float4*)&Vs[kk][tx*4];
      float av[4]={a.x,a.y,a.z,a.w}, bb[4]={bv.x,bv.y,bv.z,bv.w};
      #pragma unroll
      for (int i=0;i<4;i++)
        #pragma unroll
        for (int j=0;j<4;j++) acc[i][j] += av[i]*bb[j];
    }
    __syncthreads();
  }
  #pragma unroll
  for (int i=0;i<4;i++){
    size_t off = (size_t)(rowBase+ty*4+i)*DD + colBase + tx*4;
    st4bf(Out+off, eluf(acc[i][0]),eluf(acc[i][1]),eluf(acc[i][2]),eluf(acc[i][3]));
  }
}

// ---------- LayerNorms ----------
__global__ __launch_bounds__(256) void k_ln_x(const float* __restrict__ x, const float* __restrict__ g,
                                              const float* __restrict__ bb, bf16* __restrict__ out){
  int r = blockIdx.x*4 + (threadIdx.x>>6);
  int lane=threadIdx.x&63;
  float4 v = *(const float4*)(x + (size_t)r*DD + lane*4);
  float s = v.x+v.y+v.z+v.w;
  float s2 = v.x*v.x+v.y*v.y+v.z*v.z+v.w*v.w;
  s = wredsum(s); s2 = wredsum(s2);
  float mean = s*(1.f/256.f);
  float var = s2*(1.f/256.f) - mean*mean;
  float rstd = rsqrtf(var + 1e-5f);
  float4 gv = *(const float4*)(g+lane*4), bv = *(const float4*)(bb+lane*4);
  st4bf(out + (size_t)r*DD + lane*4,
        (v.x-mean)*rstd*gv.x+bv.x, (v.y-mean)*rstd*gv.y+bv.y,
        (v.z-mean)*rstd*gv.z+bv.z, (v.w-mean)*rstd*gv.w+bv.w);
}

__global__ __launch_bounds__(256) void k_ln_kv(const bf16* __restrict__ gout, const float* __restrict__ pe,
    const unsigned char* __restrict__ sel8, const float* __restrict__ g, const float* __restrict__ bb,
    bf16* __restrict__ out){
  int r = blockIdx.x*4 + (threadIdx.x>>6);
  int lane=threadIdx.x&63;
  int n = r & 1023;
  float4 v = make_float4(0.f,0.f,0.f,0.f);
  if (sel8[r]){
    float4 gv = ld4bf(gout + (size_t)r*DD + lane*4);
    float4 pv = *(const float4*)(pe + (size_t)n*DD + lane*4);
    v = make_float4(gv.x+pv.x, gv.y+pv.y, gv.z+pv.z, gv.w+pv.w);
  }
  float s = v.x+v.y+v.z+v.w;
  float s2 = v.x*v.x+v.y*v.y+v.z*v.z+v.w*v.w;
  s = wredsum(s); s2 = wredsum(s2);
  float mean = s*(1.f/256.f);
  float var = s2*(1.f/256.f) - mean*mean;
  float rstd = rsqrtf(var + 1e-5f);
  float4 gv = *(const float4*)(g+lane*4), bv = *(const float4*)(bb+lane*4);
  st4bf(out + (size_t)r*DD + lane*4,
        (v.x-mean)*rstd*gv.x+bv.x, (v.y-mean)*rstd*gv.y+bv.y,
        (v.z-mean)*rstd*gv.z+bv.z, (v.w-mean)*rstd*gv.w+bv.w);
}

// ---------- CA pass 1: per-row max & 1/sum of masked logits (q,k bf16) ----------
__global__ __launch_bounds__(256) void k_ca_stats(const bf16* __restrict__ q, const bf16* __restrict__ k,
    const unsigned char* __restrict__ sel8, float* __restrict__ cmax, float* __restrict__ cinv){
  __shared__ float Qt[64][68];
  __shared__ float Kt[64][68];
  __shared__ float redm[64][17];
  __shared__ float reds[64][17];
  __shared__ float redc[16];
  int tid=threadIdx.x, tx=tid&15, ty=tid>>4;
  int b=blockIdx.z, h=blockIdx.y, rowBase=blockIdx.x*64;
  size_t bOff = (size_t)b*NN;
  {
    int r=tid>>2, jc=(tid&3)*16;
    size_t qbase = (bOff + rowBase + r)*DD + h*64 + jc;
    float v[8];
    load8(q + qbase, v);
    #pragma unroll
    for (int i=0;i<8;i++) Qt[jc+i][r]=v[i];
    load8(q + qbase + 8, v);
    #pragma unroll
    for (int i=0;i<8;i++) Qt[jc+8+i][r]=v[i];
  }
  float um[4], us[4], nmk=0.f;
  #pragma unroll
  for (int i=0;i<4;i++){ um[i]=-3.0e38f; us[i]=0.f; }
  __syncthreads();
  for (int m0=0;m0<NN;m0+=64){
    {
      int r=tid>>2, jc=(tid&3)*16;
      size_t kbase = (bOff + m0 + r)*DD + h*64 + jc;
      float v[8];
      load8(k + kbase, v);
      #pragma unroll
      for (int i=0;i<8;i++) Kt[jc+i][r]=v[i];
      load8(k + kbase + 8, v);
      #pragma unroll
      for (int i=0;i<8;i++) Kt[jc+8+i][r]=v[i];
    }
    __syncthreads();
    float s[4][4]={};
    #pragma unroll 8
    for (int j=0;j<64;j++){
      float4 a=*(const float4*)&Qt[j][ty*4];
      float4 bv=*(const float4*)&Kt[j][tx*4];
      float av[4]={a.x,a.y,a.z,a.w}, bb2[4]={bv.x,bv.y,bv.z,bv.w};
      #pragma unroll
      for (int i=0;i<4;i++)
        #pragma unroll
        for (int jj=0;jj<4;jj++) s[i][jj] += av[i]*bb2[jj];
    }
    #pragma unroll
    for (int jj=0;jj<4;jj++){
      int m=m0+tx*4+jj;
      if (sel8[b*NN+m]){
        #pragma unroll
        for (int i=0;i<4;i++){
          float val=s[i][jj]*0.125f;
          float nm=fmaxf(um[i],val);
          us[i]=us[i]*exp0(um[i]-nm)+exp0(val-nm);
          um[i]=nm;
        }
      } else nmk += 1.f;
    }
    __syncthreads();
  }
  #pragma unroll
  for (int i=0;i<4;i++){ redm[ty*4+i][tx]=um[i]; reds[ty*4+i][tx]=us[i]; }
  if (ty==0) redc[tx]=nmk;
  __syncthreads();
  if (tid<64){
    int row=tid;
    float M=-3.0e38f;
    for (int t2=0;t2<16;t2++) M=fmaxf(M,redm[row][t2]);
    float cn=0.f;
    for (int t2=0;t2<16;t2++) cn+=redc[t2];
    if (cn>0.f) M=fmaxf(M,-1.0e9f);
    float S= cn*exp0(-1.0e9f-M);
    for (int t2=0;t2<16;t2++) S += reds[row][t2]*exp0(redm[row][t2]-M);
    size_t o = ((size_t)b*HC+h)*NN + rowBase + row;
    cmax[o]=M; cinv[o]=1.f/S;
  }
}

// ---------- CA pass 2: O(bf16) = softmax(QK^T masked) @ V ----------
// LDS: Qt + KP (K reused as P) + Vt = 51,200 B
__global__ __launch_bounds__(256) void k_ca_av(const bf16* __restrict__ q, const bf16* __restrict__ k,
    const bf16* __restrict__ v, const unsigned char* __restrict__ sel8,
    const float* __restrict__ cmax, const float* __restrict__ cinv, bf16* __restrict__ O){
  __shared__ float Qt[64][68];
  __shared__ float KP[64][68];
  __shared__ float Vt[64][64];
  int tid=threadIdx.x, tx=tid&15, ty=tid>>4;
  int b=blockIdx.z, h=blockIdx.y, rowBase=blockIdx.x*64;
  size_t bOff = (size_t)b*NN;
  {
    int r=tid>>2, jc=(tid&3)*16;
    size_t qbase = (bOff + rowBase + r)*DD + h*64 + jc;
    float vv[8];
    load8(q + qbase, vv);
    #pragma unroll
    for (int i=0;i<8;i++) Qt[jc+i][r]=vv[i];
    load8(q + qbase + 8, vv);
    #pragma unroll
    for (int i=0;i<8;i++) Qt[jc+8+i][r]=vv[i];
  }
  float rm[4], ri[4];
  #pragma unroll
  for (int i=0;i<4;i++){
    size_t o = ((size_t)b*HC+h)*NN + rowBase + ty*4+i;
    rm[i]=cmax[o]; ri[i]=cinv[o];
  }
  float acc[4][4]={};
  __syncthreads();
  for (int m0=0;m0<NN;m0+=64){
    {
      int r=tid>>2, jc=(tid&3)*16;
      size_t kbase = (bOff + m0 + r)*DD + h*64 + jc;
      float vv[8];
      load8(k + kbase, vv);
      #pragma unroll
      for (int i=0;i<8;i++) KP[jc+i][r]=vv[i];
      load8(k + kbase + 8, vv);
      #pragma unroll
      for (int i=0;i<8;i++) KP[jc+8+i][r]=vv[i];
      load8(v + kbase, vv);
      #pragma unroll
      for (int i=0;i<8;i++) Vt[r][jc+i]=vv[i];
      load8(v + kbase + 8, vv);
      #pragma unroll
      for (int i=0;i<8;i++) Vt[r][jc+8+i]=vv[i];
    }
    __syncthreads();
    float s[4][4]={};
    #pragma unroll 8
    for (int j=0;j<64;j++){
      float4 a=*(const float4*)&Qt[j][ty*4];
      float4 bv=*(const float4*)&KP[j][tx*4];
      float av[4]={a.x,a.y,a.z,a.w}, bb2[4]={bv.x,bv.y,bv.z,bv.w};
      #pragma unroll
      for (int i=0;i<4;i++)
        #pragma unroll
        for (int jj=0;jj<4;jj++) s[i][jj] += av[i]*bb2[jj];
    }
    __syncthreads();   // K tile fully consumed; KP becomes P tile
    #pragma unroll
    for (int jj=0;jj<4;jj++){
      int m=m0+tx*4+jj;
      bool sl = sel8[b*NN+m];
      #pragma unroll
      for (int i=0;i<4;i++){
        float val = sl ? s[i][jj]*0.125f : -1.0e9f;
        KP[tx*4+jj][ty*4+i] = exp0(val - rm[i])*ri[i];
      }
    }
    __syncthreads();
    #pragma unroll 8
    for (int kk=0;kk<64;kk++){
      float4 a=*(const float4*)&KP[kk][ty*4];
      float4 bv=*(const float4*)&Vt[kk][tx*4];
      float av[4]={a.x,a.y,a.z,a.w}, bb2[4]={bv.x,bv.y,bv.z,bv.w};
      #pragma unroll
      for (int i=0;i<4;i++)
        #pragma unroll
        for (int jj=0;jj<4;jj++) acc[i][jj] += av[i]*bb2[jj];
    }
    __syncthreads();
  }
  #pragma unroll
  for (int i=0;i<4;i++){
    size_t off = (bOff + rowBase+ty*4+i)*DD + h*64 + tx*4;
    st4bf(O+off, acc[i][0],acc[i][1],acc[i][2],acc[i][3]);
  }
}

extern "C" void kernel_launch(void* const* d_in, const int* in_sizes, int n_in,
                              void* d_out, int out_size, void* d_ws, size_t ws_size,
                              hipStream_t stream) {
  (void)in_sizes; (void)n_in; (void)out_size; (void)ws_size;
  const float* x      = (const float*)d_in[0];
  const int*   mask   = (const int*  )d_in[1];
  const float* pe     = (const float*)d_in[2];
  const float* sim_Wx = (const float*)d_in[3];
  const float* sim_Wq = (const float*)d_in[4];
  const float* adj_W  = (const float*)d_in[5];
  const float* gat_W  = (const float*)d_in[6];
  const float* gat_a1 = (const float*)d_in[7];
  const float* gat_a2 = (const float*)d_in[8];
  const float* gat_Wo = (const float*)d_in[9];
  const float* gat_ao1= (const float*)d_in[10];
  const float* gat_ao2= (const float*)d_in[11];
  const float* ln3_g  = (const float*)d_in[12];
  const float* ln3_b  = (const float*)d_in[13];
  const float* ln4_g  = (const float*)d_in[14];
  const float* ln4_b  = (const float*)d_in[15];
  const float* ca_Wq  = (const float*)d_in[16];
  const float* ca_Wk  = (const float*)d_in[17];
  const float* ca_Wv  = (const float*)d_in[18];
  const float* ca_Wp  = (const float*)d_in[19];
  const float* gamma  = (const float*)d_in[20];
  float* out    = (float*)d_out;
  float* simOut = out + (size_t)BN*DD;

  // ---- workspace layout (22 MB) ----
  char* W = (char*)d_ws;
  float* pq   = (float*)(W);            // 2048
  float* cnt  = pq + 2048;              // 16
  float* sq   = cnt + 16;               // 2048
  float* s1   = sq + 2048;              // 8192
  float* s2   = s1 + BN;
  float* rmx  = s2 + BN;
  float* rin  = rmx + BN;
  float* cam  = rin + BN;               // 32768
  float* civ  = cam + (size_t)BB*HC*NN; // 32768
  unsigned int*  conn = (unsigned int*)(W + 512*1024);   // 1 MB
  unsigned char* sel8 = (unsigned char*)(W + 1600*1024); // 8 KB
  float* S0 = (float*)(W + (size_t)2*1024*1024);         // 8 MB fp32: y -> fa -> Who
  bf16*  S0b = (bf16*)S0;                                // later: vb (bf16)
  bf16*  T0  = (bf16*)(W + (size_t)10*1024*1024);        // Wh -> kv -> Ob
  bf16*  T1  = (bf16*)(W + (size_t)14*1024*1024);        // ht -> qx -> kb
  bf16*  T2  = (bf16*)(W + (size_t)18*1024*1024);        // gout -> qb

  hipMemsetAsync(pq, 0, (2048+16)*sizeof(float), stream);
  k_posq<<<dim3(BB,16),256,0,stream>>>(x, mask, pq, cnt);
  k_sq<<<BB,256,0,stream>>>(pq, cnt, sim_Wq, sq);
  k_gemm<float,0><<<dim3(4,128),256,0,stream>>>(x, sim_Wx, S0, nullptr, nullptr, nullptr);  // y fp32
  k_simsel<<<BN/4,256,0,stream>>>(S0, sq, simOut, sel8);
  k_gemm<float,0><<<dim3(4,128),256,0,stream>>>(x, adj_W, S0, nullptr, nullptr, nullptr);   // fa fp32
  k_connect<<<dim3(16,16,BB),256,0,stream>>>(S0, sel8, conn);

  hipMemsetAsync(S0, 0, (size_t)8*1024*1024, stream);   // Who = 0
  for (int h=0;h<HG;h++){
    k_gemm<float,3><<<dim3(4,128),256,0,stream>>>(x, gat_W + (size_t)h*DD*DD, nullptr, nullptr, nullptr, T0); // Wh bf16
    k_s1s2<bf16><<<BN/4,256,0,stream>>>(T0, gat_a1 + h*DD, gat_a2 + h*DD, s1, s2);
    k_rowstats<<<BN/4,256,0,stream>>>(s1, s2, conn, rmx, rin);
    k_attn_av<bf16><<<dim3(4,128),256,0,stream>>>(s1, s2, rmx, rin, conn, T0, T1);      // ht bf16
    k_gemm<bf16,1><<<dim3(4,128),256,0,stream>>>(T1, gat_Wo + (size_t)h*DD*DD, S0, nullptr, nullptr, nullptr); // Who +=
  }
  k_s1s2<float><<<BN/4,256,0,stream>>>(S0, gat_ao1, gat_ao2, s1, s2);
  k_rowstats<<<BN/4,256,0,stream>>>(s1, s2, conn, rmx, rin);
  k_attn_av<float><<<dim3(4,128),256,0,stream>>>(s1, s2, rmx, rin, conn, S0, T2);       // gout bf16

  k_ln_x<<<BN/4,256,0,stream>>>(x, ln3_g, ln3_b, T1);                                   // qx (ht dead)
  k_ln_kv<<<BN/4,256,0,stream>>>(T2, pe, sel8, ln4_g, ln4_b, T0);                       // kv (Wh dead)
  k_gemm<bf16,3><<<dim3(4,128),256,0,stream>>>(T1, ca_Wq, nullptr, nullptr, nullptr, T2);  // qb (gout dead)
  k_gemm<bf16,3><<<dim3(4,128),256,0,stream>>>(T0, ca_Wk, nullptr, nullptr, nullptr, T1);  // kb (qx dead)
  k_gemm<bf16,3><<<dim3(4,128),256,0,stream>>>(T0, ca_Wv, nullptr, nullptr, nullptr, S0b); // vb (Who dead)
  k_ca_stats<<<dim3(16,HC,BB),256,0,stream>>>(T2, T1, sel8, cam, civ);
  k_ca_av<<<dim3(16,HC,BB),256,0,stream>>>(T2, T1, S0b, sel8, cam, civ, T0);            // Ob (kv dead)
  k_gemm<bf16,2><<<dim3(4,128),256,0,stream>>>(T0, ca_Wp, out, x, gamma, nullptr);      // out = x + gamma*o
}

// Round 5
// 1132.464 us; speedup vs baseline: 1.5633x; 1.5633x over previous
//
#include <hip/hip_runtime.h>
#include <hip/hip_bf16.h>

// GATFusionBlockPosOnly: B=8, N=1024, D=256, 8 GAT heads, 4 CA heads.
// Round 5: MFMA (16x16x32 bf16) for all matmul-shaped work.
// fp32 vector kept for threshold-critical: sim y, adjacency fa, k_connect,
// softmax stats. Weights pre-transposed+converted to bf16 once per launch.
// Workspace (29 MB):
//   [0,410KB) fp32 smalls | [512KB,1.5MB) conn | [1600KB] sel8
//   [2,10MB)  S0 fp32: y -> fa -> Who ; later (bf16) vb
//   [10,14MB) T0 bf16: Wh -> kv -> Ob
//   [14,18MB) T1 bf16: ht -> qx -> kb
//   [18,22MB) T2 bf16: gout -> qb
//   [22,23) gat_WT | [23,24) gat_WoT | [24,24.5) caW{q,k,v,p}T | [25,29) xb

#define BB 8
#define NN 1024
#define DD 256
#define HG 8
#define HC 4
#define BN (BB*NN)

typedef __hip_bfloat16 bf16;
typedef unsigned short u16;
typedef unsigned int u32;
typedef __attribute__((ext_vector_type(8))) short s8v;   // 8 bf16 (4 VGPRs)
typedef __attribute__((ext_vector_type(4))) float f4v;   // 4 fp32 acc

__device__ __forceinline__ u16 f2b(float x){
  union{ float f; unsigned u; } a; a.f = x;
  unsigned r = a.u + 0x7fff + ((a.u>>16)&1);
  return (u16)(r>>16);
}
__device__ __forceinline__ float b2f(u16 b){ return __uint_as_float(((unsigned)b)<<16); }
__device__ __forceinline__ float4 ld4bf(const bf16* p){
  uint2 u = *(const uint2*)p;
  float4 r;
  r.x=__uint_as_float(u.x<<16); r.y=__uint_as_float(u.x&0xffff0000u);
  r.z=__uint_as_float(u.y<<16); r.w=__uint_as_float(u.y&0xffff0000u);
  return r;
}
__device__ __forceinline__ void load8(const float* p, float* v){
  float4 a=*(const float4*)p, b=*(const float4*)(p+4);
  v[0]=a.x;v[1]=a.y;v[2]=a.z;v[3]=a.w;v[4]=b.x;v[5]=b.y;v[6]=b.z;v[7]=b.w;
}
__device__ __forceinline__ float wredsum(float v){
  #pragma unroll
  for(int o=32;o>0;o>>=1) v += __shfl_xor(v,o);
  return v;
}
__device__ __forceinline__ float wredmax(float v){
  #pragma unroll
  for(int o=32;o>0;o>>=1) v = fmaxf(v,__shfl_xor(v,o));
  return v;
}
__device__ __forceinline__ float eluf(float x){ return x>0.f ? x : expm1f(x); }
__device__ __forceinline__ float leakyf(float z){ return z>=0.f ? z : 0.2f*z; }
__device__ __forceinline__ float exp0(float a){ return expf(fminf(a, 0.f)); }
__device__ __forceinline__ float flushf(float v){ return (fabsf(v) < 1.0e30f) ? v : 0.f; }

// ---------- weight transpose + fp32->bf16: D[z][n][k] = S[z][k][n] ----------
__global__ __launch_bounds__(256) void k_transp(const float* __restrict__ S, u16* __restrict__ D){
  __shared__ float tl[64][65];
  int z = blockIdx.z;
  const float* src = S + (size_t)z*65536;
  u16* dst = D + (size_t)z*65536;
  int bx = blockIdx.x*64, by = blockIdx.y*64;
  int tid = threadIdx.x;
  int r = tid>>2, c0 = (tid&3)*16;
  #pragma unroll
  for (int i=0;i<16;i+=4){
    float4 v = *(const float4*)(src + (size_t)(by+r)*256 + bx + c0 + i);
    tl[r][c0+i]=v.x; tl[r][c0+i+1]=v.y; tl[r][c0+i+2]=v.z; tl[r][c0+i+3]=v.w;
  }
  __syncthreads();
  u16 tmp[16];
  #pragma unroll
  for (int i=0;i<16;i++) tmp[i] = f2b(tl[c0+i][r]);
  *(uint4*)(dst + (size_t)(bx+r)*256 + by + c0) = *(uint4*)&tmp[0];
  *(uint4*)(dst + (size_t)(bx+r)*256 + by + c0 + 8) = *(uint4*)&tmp[8];
}

// ---------- fp32 -> bf16 bulk convert ----------
__global__ __launch_bounds__(256) void k_tob(const float* __restrict__ X, u16* __restrict__ Y){
  size_t i = ((size_t)blockIdx.x*256 + threadIdx.x)*8;
  float v[8]; load8(X+i, v);
  u16 t[8];
  #pragma unroll
  for (int j=0;j<8;j++) t[j]=f2b(v[j]);
  *(uint4*)(Y+i) = *(uint4*)&t[0];
}

// ---------- pos_query partial sums ----------
__global__ __launch_bounds__(256) void k_posq(const float* __restrict__ x, const int* __restrict__ mask,
                                              float* __restrict__ pq, float* __restrict__ cnt){
  int b = blockIdx.x, chunk = blockIdx.y;
  int d = threadIdx.x;
  int n0 = chunk*64;
  float acc = 0.f; float c = 0.f;
  for (int i=0;i<64;i++){
    int n = n0+i;
    if (mask[b*NN+n]==1){ acc += x[((size_t)(b*NN+n))*DD + d]; c += 1.f; }
  }
  atomicAdd(&pq[b*DD+d], acc);
  if (d==0) atomicAdd(&cnt[b], c);
}

__global__ __launch_bounds__(256) void k_sq(const float* __restrict__ pq, const float* __restrict__ cnt,
                                            const float* __restrict__ Wq, float* __restrict__ sq){
  int b = blockIdx.x, e = threadIdx.x;
  float inv = 1.f / fmaxf(cnt[b], 1.f);
  float acc=0.f;
  for (int d0=0; d0<DD; d0++) acc += (pq[b*DD+d0]*inv) * Wq[d0*DD+e];
  sq[b*DD+e] = acc;
}

__global__ __launch_bounds__(256) void k_simsel(const float* __restrict__ y, const float* __restrict__ sq,
                                                float* __restrict__ simOut, unsigned char* __restrict__ sel8){
  int r = blockIdx.x*4 + (threadIdx.x>>6);
  int lane = threadIdx.x & 63;
  int b = r>>10;
  float4 yv = *(const float4*)(y + (size_t)r*DD + lane*4);
  float4 qv = *(const float4*)(sq + b*DD + lane*4);
  float p = yv.x*qv.x + yv.y*qv.y + yv.z*qv.z + yv.w*qv.w;
  p = wredsum(p);
  if (lane==0){
    float s = p * 0.0625f;
    float sim = 1.f/(1.f+expf(-s));
    simOut[r] = sim;
    sel8[r] = (sim > 0.97f) ? 1 : 0;
  }
}

// ---------- fp32 vector GEMM (threshold-critical): C = A@B ----------
__global__ __launch_bounds__(256) void k_gemm_f32(const float* __restrict__ A, const float* __restrict__ Bw,
                                                  float* __restrict__ C){
  __shared__ float As[32][68];
  __shared__ float Bs[32][64];
  int tid = threadIdx.x;
  int tx = tid & 15, ty = tid >> 4;
  int colBase = blockIdx.x*64, rowBase = blockIdx.y*64;
  float acc[4][4] = {};
  for (int k0=0;k0<DD;k0+=32){
    {
      int r = tid>>2, kc = (tid&3)*8;
      float v[8]; load8(A + (size_t)(rowBase+r)*DD + k0+kc, v);
      #pragma unroll
      for (int i=0;i<8;i++) As[kc+i][r]=v[i];
    }
    {
      int kr = tid>>3, cc = (tid&7)*8;
      float v[8]; load8(Bw + (size_t)(k0+kr)*DD + colBase+cc, v);
      #pragma unroll
      for (int i=0;i<8;i++) Bs[kr][cc+i]=v[i];
    }
    __syncthreads();
    #pragma unroll
    for (int kk=0;kk<32;kk++){
      float4 a = *(const float4*)&As[kk][ty*4];
      float4 b = *(const float4*)&Bs[kk][tx*4];
      float av[4]={a.x,a.y,a.z,a.w}, bv[4]={b.x,b.y,b.z,b.w};
      #pragma unroll
      for (int i=0;i<4;i++)
        #pragma unroll
        for (int j=0;j<4;j++) acc[i][j] += av[i]*bv[j];
    }
    __syncthreads();
  }
  #pragma unroll
  for (int i=0;i<4;i++){
    size_t off = (size_t)(rowBase+ty*4+i)*DD + colBase + tx*4;
    *(float4*)(C+off) = make_float4(acc[i][0],acc[i][1],acc[i][2],acc[i][3]);
  }
}

// ---------- MFMA GEMM: C[8192,256] = A(bf16) @ B, BT[n][k] bf16 ----------
// EPI: 1 = fp32 accumulate, 2 = final out=x+gamma*acc fp32 flushed, 3 = bf16 store
template<int EPI>
__global__ __launch_bounds__(256) void k_mgemm(const u16* __restrict__ A, const u16* __restrict__ BT,
    float* __restrict__ C, const float* __restrict__ Xres, const float* __restrict__ gamma,
    u16* __restrict__ Obf){
  __shared__ __align__(16) u16 Als[64][32];
  __shared__ __align__(16) u16 Bls[64][32];
  int tid = threadIdx.x;
  int w = tid>>6, lane = tid&63, L = lane&15, q = lane>>4;
  int colBase = blockIdx.x*64, rowBase = blockIdx.y*64;
  f4v zero = {0.f,0.f,0.f,0.f};
  f4v acc[4] = {zero,zero,zero,zero};
  int sr = tid>>2, skc = (tid&3)*8;
  for (int k0=0;k0<DD;k0+=32){
    __syncthreads();
    *(uint4*)&Als[sr][skc] = *(const uint4*)(A  + (size_t)(rowBase+sr)*DD + k0+skc);
    *(uint4*)&Bls[sr][skc] = *(const uint4*)(BT + (size_t)(colBase+sr)*DD + k0+skc);
    __syncthreads();
    s8v af = *(const s8v*)&Als[w*16 + L][q*8];
    #pragma unroll
    for (int t=0;t<4;t++){
      s8v bfr = *(const s8v*)&Bls[t*16 + L][q*8];
      acc[t] = __builtin_amdgcn_mfma_f32_16x16x32_bf16(af, bfr, acc[t], 0,0,0);
    }
  }
  #pragma unroll
  for (int t=0;t<4;t++){
    int col = colBase + t*16 + L;
    #pragma unroll
    for (int reg=0;reg<4;reg++){
      int row = rowBase + w*16 + q*4 + reg;
      size_t off = (size_t)row*DD + col;
      float v = acc[t][reg];
      if constexpr (EPI==1){ C[off] += v; }
      else if constexpr (EPI==2){ C[off] = flushf(Xres[off] + gamma[col]*v); }
      else { Obf[off] = f2b(v); }
    }
  }
}

// ---------- connectivity bitmask (fp32, sign-critical) ----------
__global__ __launch_bounds__(256) void k_connect(const float* __restrict__ fa, const unsigned char* __restrict__ sel8,
                                                 u32* __restrict__ conn){
  __shared__ float As[32][68];
  __shared__ float Bs2[32][68];
  __shared__ unsigned char sg[64][64];
  int tid=threadIdx.x, tx=tid&15, ty=tid>>4;
  int b = blockIdx.z;
  int mBase = blockIdx.x*64, nBase = blockIdx.y*64;
  const float* fab = fa + (size_t)b*NN*DD;
  float acc[4][4]={};
  for (int k0=0;k0<DD;k0+=32){
    int r=tid>>2, kc=(tid&3)*8;
    { float v[8]; load8(fab + (size_t)(nBase+r)*DD + k0+kc, v);
      #pragma unroll
      for (int i=0;i<8;i++) As[kc+i][r]=v[i]; }
    { float v[8]; load8(fab + (size_t)(mBase+r)*DD + k0+kc, v);
      #pragma unroll
      for (int i=0;i<8;i++) Bs2[kc+i][r]=v[i]; }
    __syncthreads();
    #pragma unroll
    for (int kk=0;kk<32;kk++){
      float4 a=*(const float4*)&As[kk][ty*4];
      float4 bv=*(const float4*)&Bs2[kk][tx*4];
      float av[4]={a.x,a.y,a.z,a.w}, bb[4]={bv.x,bv.y,bv.z,bv.w};
      #pragma unroll
      for (int i=0;i<4;i++)
        #pragma unroll
        for (int j=0;j<4;j++) acc[i][j] += av[i]*bb[j];
    }
    __syncthreads();
  }
  #pragma unroll
  for (int i=0;i<4;i++)
    #pragma unroll
    for (int j=0;j<4;j++) sg[ty*4+i][tx*4+j] = acc[i][j] > 0.f;
  __syncthreads();
  if (tid<128){
    int row=tid>>1, w=tid&1;
    int nG = nBase+row;
    u32 word=0;
    if (sel8[b*NN + nG]){
      for (int j=0;j<32;j++){
        int m = mBase + w*32 + j;
        if (sg[row][w*32+j] && sel8[b*NN+m]) word |= (1u<<j);
      }
    }
    conn[((size_t)b*NN + nG)*32 + (mBase>>5) + w] = word;
  }
}

// ---------- s1/s2 = V @ a1, V @ a2 ----------
template<typename VT>
__global__ __launch_bounds__(256) void k_s1s2(const VT* __restrict__ V, const float* __restrict__ a1,
                                              const float* __restrict__ a2, float* __restrict__ s1, float* __restrict__ s2){
  int r = blockIdx.x*4 + (threadIdx.x>>6);
  int lane = threadIdx.x&63;
  float4 v;
  if constexpr (sizeof(VT)==2) v = ld4bf((const bf16*)V + (size_t)r*DD + lane*4);
  else                         v = *(const float4*)((const float*)V + (size_t)r*DD + lane*4);
  float4 w1 = *(const float4*)(a1+lane*4), w2 = *(const float4*)(a2+lane*4);
  float d1 = v.x*w1.x+v.y*w1.y+v.z*w1.z+v.w*w1.w;
  float d2 = v.x*w2.x+v.y*w2.y+v.z*w2.z+v.w*w2.w;
  d1=wredsum(d1); d2=wredsum(d2);
  if (lane==0){ s1[r]=d1; s2[r]=d2; }
}

// ---------- GAT row softmax stats ----------
__global__ __launch_bounds__(256) void k_rowstats(const float* __restrict__ s1, const float* __restrict__ s2,
    const u32* __restrict__ conn, float* __restrict__ rmax, float* __restrict__ rinv){
  int r = blockIdx.x*4 + (threadIdx.x>>6);
  int lane = threadIdx.x&63;
  int b = r>>10;
  float sr = s1[r];
  float e[16];
  float mx = -3.0e38f;
  #pragma unroll
  for (int t=0;t<16;t++){
    int m = lane + t*64;
    u32 w = conn[(size_t)r*32 + (m>>5)];
    float ev;
    if ((w>>(m&31))&1u){ ev = leakyf(sr + s2[b*NN+m]); }
    else ev = -9.0e15f;
    e[t]=ev; mx = fmaxf(mx,ev);
  }
  mx = wredmax(mx);
  float sm=0.f;
  #pragma unroll
  for (int t=0;t<16;t++) sm += exp0(e[t]-mx);
  sm = wredsum(sm);
  if (lane==0){ rmax[r]=mx; rinv[r]=1.f/sm; }
}

// ---------- MFMA GAT attention: Out(bf16) = elu(P @ V), P built in A-layout regs ----------
template<typename VT>
__global__ __launch_bounds__(256) void k_mattn(const float* __restrict__ s1, const float* __restrict__ s2,
    const float* __restrict__ rmax, const float* __restrict__ rinv,
    const u32* __restrict__ conn, const VT* __restrict__ V, u16* __restrict__ Out){
  __shared__ __align__(16) u16 Vt[64][40];   // Vt[d][m], chunk m=32
  int tid=threadIdx.x;
  int w = tid>>6, lane = tid&63, L = lane&15, q = lane>>4;
  int colBase = blockIdx.x*64, rowBase = blockIdx.y*64;
  int b = rowBase>>10;
  size_t bOff = (size_t)b*NN;
  int r = rowBase + w*16 + L;                // this lane's A row
  float s1v = s1[r], rmv = rmax[r], riv = rinv[r];
  f4v zero = {0.f,0.f,0.f,0.f};
  f4v acc[4] = {zero,zero,zero,zero};
  int sm_ = tid&31, sd0 = (tid>>5)*8;
  for (int k0=0;k0<NN;k0+=32){
    __syncthreads();
    {  // stage V chunk [32 m][64 d] transposed -> Vt[d][m]
      const VT* vp = V + (bOff + k0 + sm_)*(size_t)DD + colBase + sd0;
      u16 tmp[8];
      if constexpr (sizeof(VT)==2){
        uint4 u = *(const uint4*)vp;
        *(uint4*)&tmp[0] = u;
      } else {
        float vv[8]; load8((const float*)vp, vv);
        #pragma unroll
        for (int i=0;i<8;i++) tmp[i]=f2b(vv[i]);
      }
      #pragma unroll
      for (int i=0;i<8;i++) Vt[sd0+i][sm_] = tmp[i];
    }
    // P frag in registers: k = k0 + q*8 + j
    u32 cw = conn[(size_t)r*32 + (k0>>5)];
    s8v pf;
    #pragma unroll
    for (int j=0;j<8;j++){
      int m = k0 + q*8 + j;
      float ev = ((cw>>(q*8+j))&1u) ? leakyf(s1v + s2[bOff+m]) : -9.0e15f;
      pf[j] = (short)f2b(exp0(ev - rmv)*riv);
    }
    __syncthreads();
    #pragma unroll
    for (int t=0;t<4;t++){
      s8v vf = *(const s8v*)&Vt[t*16 + L][q*8];
      acc[t] = __builtin_amdgcn_mfma_f32_16x16x32_bf16(pf, vf, acc[t], 0,0,0);
    }
  }
  #pragma unroll
  for (int t=0;t<4;t++){
    int col = colBase + t*16 + L;
    #pragma unroll
    for (int reg=0;reg<4;reg++){
      int row = rowBase + w*16 + q*4 + reg;
      Out[(size_t)row*DD + col] = f2b(eluf(acc[t][reg]));
    }
  }
}

// ---------- LayerNorms ----------
__global__ __launch_bounds__(256) void k_ln_x(const float* __restrict__ x, const float* __restrict__ g,
                                              const float* __restrict__ bb, u16* __restrict__ out){
  int r = blockIdx.x*4 + (threadIdx.x>>6);
  int lane=threadIdx.x&63;
  float4 v = *(const float4*)(x + (size_t)r*DD + lane*4);
  float s = v.x+v.y+v.z+v.w;
  float s2 = v.x*v.x+v.y*v.y+v.z*v.z+v.w*v.w;
  s = wredsum(s); s2 = wredsum(s2);
  float mean = s*(1.f/256.f);
  float var = s2*(1.f/256.f) - mean*mean;
  float rstd = rsqrtf(var + 1e-5f);
  float4 gv = *(const float4*)(g+lane*4), bv = *(const float4*)(bb+lane*4);
  u16 t[4];
  t[0]=f2b((v.x-mean)*rstd*gv.x+bv.x); t[1]=f2b((v.y-mean)*rstd*gv.y+bv.y);
  t[2]=f2b((v.z-mean)*rstd*gv.z+bv.z); t[3]=f2b((v.w-mean)*rstd*gv.w+bv.w);
  *(uint2*)(out + (size_t)r*DD + lane*4) = *(uint2*)&t[0];
}

__global__ __launch_bounds__(256) void k_ln_kv(const u16* __restrict__ gout, const float* __restrict__ pe,
    const unsigned char* __restrict__ sel8, const float* __restrict__ g, const float* __restrict__ bb,
    u16* __restrict__ out){
  int r = blockIdx.x*4 + (threadIdx.x>>6);
  int lane=threadIdx.x&63;
  int n = r & 1023;
  float4 v = make_float4(0.f,0.f,0.f,0.f);
  if (sel8[r]){
    float4 gv = ld4bf((const bf16*)gout + (size_t)r*DD + lane*4);
    float4 pv = *(const float4*)(pe + (size_t)n*DD + lane*4);
    v = make_float4(gv.x+pv.x, gv.y+pv.y, gv.z+pv.z, gv.w+pv.w);
  }
  float s = v.x+v.y+v.z+v.w;
  float s2 = v.x*v.x+v.y*v.y+v.z*v.z+v.w*v.w;
  s = wredsum(s); s2 = wredsum(s2);
  float mean = s*(1.f/256.f);
  float var = s2*(1.f/256.f) - mean*mean;
  float rstd = rsqrtf(var + 1e-5f);
  float4 gv = *(const float4*)(g+lane*4), bv = *(const float4*)(bb+lane*4);
  u16 t[4];
  t[0]=f2b((v.x-mean)*rstd*gv.x+bv.x); t[1]=f2b((v.y-mean)*rstd*gv.y+bv.y);
  t[2]=f2b((v.z-mean)*rstd*gv.z+bv.z); t[3]=f2b((v.w-mean)*rstd*gv.w+bv.w);
  *(uint2*)(out + (size_t)r*DD + lane*4) = *(uint2*)&t[0];
}

// ---------- MFMA CA stats: per-row max & 1/sum over masked logits ----------
__global__ __launch_bounds__(256) void k_mca_stats(const u16* __restrict__ q, const u16* __restrict__ k,
    const unsigned char* __restrict__ sel8, float* __restrict__ cmax, float* __restrict__ cinv){
  __shared__ __align__(16) u16 Qls[64][72];
  __shared__ __align__(16) u16 Kls[64][72];
  __shared__ float cw4[4];
  int tid=threadIdx.x;
  int w = tid>>6, lane = tid&63, L = lane&15, qd = lane>>4;
  int b=blockIdx.z, h=blockIdx.y, rowBase=blockIdx.x*64;
  size_t bOff = (size_t)b*NN;
  // cn = #unselected columns (same for all rows)
  {
    float c = 0.f;
    #pragma unroll
    for (int i=0;i<4;i++) c += sel8[b*NN + tid*4 + i] ? 0.f : 1.f;
    c = wredsum(c);
    if (lane==0) cw4[w]=c;
  }
  {
    int r=tid>>2, c0=(tid&3)*16;
    size_t base = (bOff + rowBase + r)*(size_t)DD + h*64 + c0;
    *(uint4*)&Qls[r][c0]   = *(const uint4*)(q + base);
    *(uint4*)&Qls[r][c0+8] = *(const uint4*)(q + base + 8);
  }
  float um[4], us[4];
  #pragma unroll
  for (int i=0;i<4;i++){ um[i]=-3.0e38f; us[i]=0.f; }
  for (int m0=0;m0<NN;m0+=64){
    __syncthreads();
    {
      int r=tid>>2, c0=(tid&3)*16;
      size_t base = (bOff + m0 + r)*(size_t)DD + h*64 + c0;
      *(uint4*)&Kls[r][c0]   = *(const uint4*)(k + base);
      *(uint4*)&Kls[r][c0+8] = *(const uint4*)(k + base + 8);
    }
    __syncthreads();
    f4v zero = {0.f,0.f,0.f,0.f};
    f4v sa[4] = {zero,zero,zero,zero};
    #pragma unroll
    for (int kc=0;kc<64;kc+=32){
      s8v af = *(const s8v*)&Qls[w*16 + L][kc + qd*8];
      #pragma unroll
      for (int t=0;t<4;t++){
        s8v bfr = *(const s8v*)&Kls[t*16 + L][kc + qd*8];
        sa[t] = __builtin_amdgcn_mfma_f32_16x16x32_bf16(af, bfr, sa[t], 0,0,0);
      }
    }
    #pragma unroll
    for (int t=0;t<4;t++){
      int m = m0 + t*16 + L;
      if (sel8[b*NN+m]){
        #pragma unroll
        for (int reg=0;reg<4;reg++){
          float val = sa[t][reg]*0.125f;
          float nm = fmaxf(um[reg], val);
          us[reg] = us[reg]*exp0(um[reg]-nm) + exp0(val-nm);
          um[reg] = nm;
        }
      }
    }
  }
  // reduce across the 16 lanes sharing each row (xor within L)
  #pragma unroll
  for (int off=1;off<16;off<<=1){
    #pragma unroll
    for (int reg=0;reg<4;reg++){
      float om = __shfl_xor(um[reg], off);
      float os = __shfl_xor(us[reg], off);
      float nm = fmaxf(um[reg], om);
      us[reg] = us[reg]*exp0(um[reg]-nm) + os*exp0(om-nm);
      um[reg] = nm;
    }
  }
  __syncthreads();
  float cn = cw4[0]+cw4[1]+cw4[2]+cw4[3];
  if (L==0){
    #pragma unroll
    for (int reg=0;reg<4;reg++){
      int row = rowBase + w*16 + qd*4 + reg;
      float M = um[reg];
      if (cn>0.f) M = fmaxf(M, -1.0e9f);
      float S = cn*exp0(-1.0e9f - M) + us[reg]*exp0(um[reg]-M);
      size_t o = ((size_t)b*HC+h)*NN + row;
      cmax[o]=M; cinv[o]=1.f/S;
    }
  }
}

// ---------- MFMA CA attention: O(bf16) = softmax(QK^T masked) @ V ----------
__global__ __launch_bounds__(256) void k_mca_av(const u16* __restrict__ q, const u16* __restrict__ k,
    const u16* __restrict__ v, const unsigned char* __restrict__ sel8,
    const float* __restrict__ cmax, const float* __restrict__ cinv, u16* __restrict__ O){
  __shared__ __align__(16) u16 Qls[64][72];
  __shared__ __align__(16) u16 KP[64][72];   // K tile, then P tile
  __shared__ __align__(16) u16 Vt[64][72];   // Vt[d][m]
  int tid=threadIdx.x;
  int w = tid>>6, lane = tid&63, L = lane&15, qd = lane>>4;
  int b=blockIdx.z, h=blockIdx.y, rowBase=blockIdx.x*64;
  size_t bOff = (size_t)b*NN;
  {
    int r=tid>>2, c0=(tid&3)*16;
    size_t base = (bOff + rowBase + r)*(size_t)DD + h*64 + c0;
    *(uint4*)&Qls[r][c0]   = *(const uint4*)(q + base);
    *(uint4*)&Qls[r][c0+8] = *(const uint4*)(q + base + 8);
  }
  float rm[4], ri[4];
  #pragma unroll
  for (int reg=0;reg<4;reg++){
    size_t o = ((size_t)b*HC+h)*NN + rowBase + w*16 + qd*4 + reg;
    rm[reg]=cmax[o]; ri[reg]=cinv[o];
  }
  f4v zero = {0.f,0.f,0.f,0.f};
  f4v acc[4] = {zero,zero,zero,zero};
  int svm = tid&63, svd0 = (tid>>6)*16;      // V staging: m=tid&63, 16 d's per thread
  for (int m0=0;m0<NN;m0+=64){
    __syncthreads();
    {
      int r=tid>>2, c0=(tid&3)*16;
      size_t base = (bOff + m0 + r)*(size_t)DD + h*64 + c0;
      *(uint4*)&KP[r][c0]   = *(const uint4*)(k + base);
      *(uint4*)&KP[r][c0+8] = *(const uint4*)(k + base + 8);
      // V transposed: read v[m][d0..d0+15], scatter into Vt[d][m]
      size_t vb_ = (bOff + m0 + svm)*(size_t)DD + h*64 + svd0;
      uint4 u0 = *(const uint4*)(v + vb_);
      uint4 u1 = *(const uint4*)(v + vb_ + 8);
      u16 tmp[16];
      *(uint4*)&tmp[0]=u0; *(uint4*)&tmp[8]=u1;
      #pragma unroll
      for (int i=0;i<16;i++) Vt[svd0+i][svm] = tmp[i];
    }
    __syncthreads();
    f4v sa[4] = {zero,zero,zero,zero};
    #pragma unroll
    for (int kc=0;kc<64;kc+=32){
      s8v af = *(const s8v*)&Qls[w*16 + L][kc + qd*8];
      #pragma unroll
      for (int t=0;t<4;t++){
        s8v bfr = *(const s8v*)&KP[t*16 + L][kc + qd*8];
        sa[t] = __builtin_amdgcn_mfma_f32_16x16x32_bf16(af, bfr, sa[t], 0,0,0);
      }
    }
    __syncthreads();   // K tile consumed -> KP becomes P tile
    #pragma unroll
    for (int t=0;t<4;t++){
      int m = m0 + t*16 + L;
      bool sl = sel8[b*NN+m];
      #pragma unroll
      for (int reg=0;reg<4;reg++){
        float val = sl ? sa[t][reg]*0.125f : -1.0e9f;
        KP[w*16 + qd*4 + reg][t*16 + L] = f2b(exp0(val - rm[reg])*ri[reg]);
      }
    }
    __syncthreads();
    #pragma unroll
    for (int mc=0;mc<64;mc+=32){
      s8v pf = *(const s8v*)&KP[w*16 + L][mc + qd*8];
      #pragma unroll
      for (int t=0;t<4;t++){
        s8v vf = *(const s8v*)&Vt[t*16 + L][mc + qd*8];
        acc[t] = __builtin_amdgcn_mfma_f32_16x16x32_bf16(pf, vf, acc[t], 0,0,0);
      }
    }
  }
  #pragma unroll
  for (int t=0;t<4;t++){
    int col = h*64 + t*16 + L;
    #pragma unroll
    for (int reg=0;reg<4;reg++){
      int row = rowBase + w*16 + qd*4 + reg;
      O[(bOff + row)*(size_t)DD + col] = f2b(acc[t][reg]);
    }
  }
}

extern "C" void kernel_launch(void* const* d_in, const int* in_sizes, int n_in,
                              void* d_out, int out_size, void* d_ws, size_t ws_size,
                              hipStream_t stream) {
  (void)in_sizes; (void)n_in; (void)out_size; (void)ws_size;
  const float* x      = (const float*)d_in[0];
  const int*   mask   = (const int*  )d_in[1];
  const float* pe     = (const float*)d_in[2];
  const float* sim_Wx = (const float*)d_in[3];
  const float* sim_Wq = (const float*)d_in[4];
  const float* adj_W  = (const float*)d_in[5];
  const float* gat_W  = (const float*)d_in[6];
  const float* gat_a1 = (const float*)d_in[7];
  const float* gat_a2 = (const float*)d_in[8];
  const float* gat_Wo = (const float*)d_in[9];
  const float* gat_ao1= (const float*)d_in[10];
  const float* gat_ao2= (const float*)d_in[11];
  const float* ln3_g  = (const float*)d_in[12];
  const float* ln3_b  = (const float*)d_in[13];
  const float* ln4_g  = (const float*)d_in[14];
  const float* ln4_b  = (const float*)d_in[15];
  const float* ca_Wq  = (const float*)d_in[16];
  const float* ca_Wk  = (const float*)d_in[17];
  const float* ca_Wv  = (const float*)d_in[18];
  const float* ca_Wp  = (const float*)d_in[19];
  const float* gamma  = (const float*)d_in[20];
  float* out    = (float*)d_out;
  float* simOut = out + (size_t)BN*DD;

  char* W = (char*)d_ws;
  float* pq   = (float*)(W);
  float* cnt  = pq + 2048;
  float* sq   = cnt + 16;
  float* s1   = sq + 2048;
  float* s2   = s1 + BN;
  float* rmx  = s2 + BN;
  float* rin  = rmx + BN;
  float* cam  = rin + BN;
  float* civ  = cam + (size_t)BB*HC*NN;
  u32*  conn = (u32*)(W + 512*1024);
  unsigned char* sel8 = (unsigned char*)(W + 1600*1024);
  float* S0  = (float*)(W + (size_t)2*1024*1024);     // 8MB fp32: y -> fa -> Who
  u16*   S0b = (u16*)S0;                              // later: vb
  u16*   T0  = (u16*)(W + (size_t)10*1024*1024);      // Wh -> kv -> Ob
  u16*   T1  = (u16*)(W + (size_t)14*1024*1024);      // ht -> qx -> kb
  u16*   T2  = (u16*)(W + (size_t)18*1024*1024);      // gout -> qb
  u16*   WT0 = (u16*)(W + (size_t)22*1024*1024);      // gat_W^T (8 x 256x256)
  u16*   WT1 = (u16*)(W + (size_t)23*1024*1024);      // gat_Wo^T
  u16*   WQT = (u16*)(W + (size_t)24*1024*1024);
  u16*   WKT = WQT + 65536;
  u16*   WVT = WKT + 65536;
  u16*   WPT = WVT + 65536;
  u16*   xb  = (u16*)(W + (size_t)25*1024*1024);      // x bf16 (4MB)

  // prep: conversions/transposes
  k_tob<<<BN*DD/(256*8),256,0,stream>>>(x, xb);
  k_transp<<<dim3(4,4,HG),256,0,stream>>>(gat_W,  WT0);
  k_transp<<<dim3(4,4,HG),256,0,stream>>>(gat_Wo, WT1);
  k_transp<<<dim3(4,4,1),256,0,stream>>>(ca_Wq, WQT);
  k_transp<<<dim3(4,4,1),256,0,stream>>>(ca_Wk, WKT);
  k_transp<<<dim3(4,4,1),256,0,stream>>>(ca_Wv, WVT);
  k_transp<<<dim3(4,4,1),256,0,stream>>>(ca_Wp, WPT);

  hipMemsetAsync(pq, 0, (2048+16)*sizeof(float), stream);
  k_posq<<<dim3(BB,16),256,0,stream>>>(x, mask, pq, cnt);
  k_sq<<<BB,256,0,stream>>>(pq, cnt, sim_Wq, sq);
  k_gemm_f32<<<dim3(4,128),256,0,stream>>>(x, sim_Wx, S0);     // y fp32
  k_simsel<<<BN/4,256,0,stream>>>(S0, sq, simOut, sel8);
  k_gemm_f32<<<dim3(4,128),256,0,stream>>>(x, adj_W, S0);      // fa fp32
  k_connect<<<dim3(16,16,BB),256,0,stream>>>(S0, sel8, conn);

  hipMemsetAsync(S0, 0, (size_t)8*1024*1024, stream);          // Who = 0
  for (int h=0;h<HG;h++){
    k_mgemm<3><<<dim3(4,128),256,0,stream>>>(xb, WT0 + (size_t)h*65536, nullptr, nullptr, nullptr, T0); // Wh
    k_s1s2<u16><<<BN/4,256,0,stream>>>(T0, gat_a1 + h*DD, gat_a2 + h*DD, s1, s2);
    k_rowstats<<<BN/4,256,0,stream>>>(s1, s2, conn, rmx, rin);
    k_mattn<u16><<<dim3(4,128),256,0,stream>>>(s1, s2, rmx, rin, conn, T0, T1);                          // ht
    k_mgemm<1><<<dim3(4,128),256,0,stream>>>(T1, WT1 + (size_t)h*65536, S0, nullptr, nullptr, nullptr);  // Who +=
  }
  k_s1s2<float><<<BN/4,256,0,stream>>>(S0, gat_ao1, gat_ao2, s1, s2);
  k_rowstats<<<BN/4,256,0,stream>>>(s1, s2, conn, rmx, rin);
  k_mattn<float><<<dim3(4,128),256,0,stream>>>(s1, s2, rmx, rin, conn, S0, T2);                          // gout

  k_ln_x<<<BN/4,256,0,stream>>>(x, ln3_g, ln3_b, T1);                          // qx
  k_ln_kv<<<BN/4,256,0,stream>>>(T2, pe, sel8, ln4_g, ln4_b, T0);              // kv
  k_mgemm<3><<<dim3(4,128),256,0,stream>>>(T1, WQT, nullptr, nullptr, nullptr, T2);  // qb
  k_mgemm<3><<<dim3(4,128),256,0,stream>>>(T0, WKT, nullptr, nullptr, nullptr, T1);  // kb
  k_mgemm<3><<<dim3(4,128),256,0,stream>>>(T0, WVT, nullptr, nullptr, nullptr, S0b); // vb
  k_mca_stats<<<dim3(16,HC,BB),256,0,stream>>>(T2, T1, sel8, cam, civ);
  k_mca_av<<<dim3(16,HC,BB),256,0,stream>>>(T2, T1, S0b, sel8, cam, civ, T0);        // Ob
  k_mgemm<2><<<dim3(4,128),256,0,stream>>>(T0, WPT, out, x, gamma, nullptr);         // out = x + gamma*o
}

// Round 7
// 934.522 us; speedup vs baseline: 1.8944x; 1.2118x over previous
//
#include <hip/hip_runtime.h>
#include <hip/hip_bf16.h>

// GATFusionBlockPosOnly: B=8, N=1024, D=256, 8 GAT heads, 4 CA heads.
// Round 7: R6 with the MFMA macro fixed (builtin needs cbsz/abid/blgp = 0,0,0).
//   (1) no-LDS direct-global MFMA GEMM (reg double-buffered, 0 barriers)
//   (2) split-bf16 (hi+lo, 3-term) MFMA for threshold-critical GEMMs
//   (3) GAT heads batched (grid.z=8) when ws_size >= 98MB; per-head fallback.

#define BB 8
#define NN 1024
#define DD 256
#define HG 8
#define HC 4
#define BN (BB*NN)

typedef unsigned short u16;
typedef unsigned int u32;
typedef unsigned char u8;
typedef __attribute__((ext_vector_type(8))) short s8v;   // 8 bf16
typedef __attribute__((ext_vector_type(4))) float f4v;   // 4 fp32 acc
#define MFMA(a,b,c) __builtin_amdgcn_mfma_f32_16x16x32_bf16((a),(b),(c),0,0,0)

__device__ __forceinline__ u16 f2b(float x){
  union{ float f; unsigned u; } a; a.f = x;
  unsigned r = a.u + 0x7fff + ((a.u>>16)&1);
  return (u16)(r>>16);
}
__device__ __forceinline__ float b2f(u16 b){ return __uint_as_float(((unsigned)b)<<16); }
__device__ __forceinline__ float4 ld4bf(const u16* p){
  uint2 u = *(const uint2*)p;
  float4 r;
  r.x=__uint_as_float(u.x<<16); r.y=__uint_as_float(u.x&0xffff0000u);
  r.z=__uint_as_float(u.y<<16); r.w=__uint_as_float(u.y&0xffff0000u);
  return r;
}
__device__ __forceinline__ void load8(const float* p, float* v){
  float4 a=*(const float4*)p, b=*(const float4*)(p+4);
  v[0]=a.x;v[1]=a.y;v[2]=a.z;v[3]=a.w;v[4]=b.x;v[5]=b.y;v[6]=b.z;v[7]=b.w;
}
__device__ __forceinline__ float wredsum(float v){
  #pragma unroll
  for(int o=32;o>0;o>>=1) v += __shfl_xor(v,o);
  return v;
}
__device__ __forceinline__ float wredmax(float v){
  #pragma unroll
  for(int o=32;o>0;o>>=1) v = fmaxf(v,__shfl_xor(v,o));
  return v;
}
__device__ __forceinline__ float eluf(float x){ return x>0.f ? x : expm1f(x); }
__device__ __forceinline__ float leakyf(float z){ return z>=0.f ? z : 0.2f*z; }
__device__ __forceinline__ float exp0(float a){ return expf(fminf(a, 0.f)); }
__device__ __forceinline__ float flushf(float v){ return (fabsf(v) < 1.0e30f) ? v : 0.f; }

// ---------- fp32 -> (hi,lo) bf16 split ----------
__global__ __launch_bounds__(256) void k_split(const float* __restrict__ X, u16* __restrict__ H, u16* __restrict__ Lo){
  size_t i = ((size_t)blockIdx.x*256 + threadIdx.x)*8;
  float v[8]; load8(X+i, v);
  u16 hh[8], ll[8];
  #pragma unroll
  for (int j=0;j<8;j++){ hh[j]=f2b(v[j]); ll[j]=f2b(v[j]-b2f(hh[j])); }
  *(uint4*)(H+i)=*(uint4*)&hh[0];
  *(uint4*)(Lo+i)=*(uint4*)&ll[0];
}

// ---------- transpose fp32 [R][C] -> bf16 [C][R]; grid (C/64, R/64, slices) ----------
__global__ __launch_bounds__(256) void k_transpose(const float* __restrict__ S, u16* __restrict__ D,
                                                   int R, int sliceElems){
  __shared__ float tl[64][65];
  const float* src = S + (size_t)blockIdx.z*sliceElems;
  u16* dst = D + (size_t)blockIdx.z*sliceElems;
  int C = gridDim.x*64;
  int bx=blockIdx.x*64, by=blockIdx.y*64;
  int tid=threadIdx.x, r=tid>>2, c0=(tid&3)*16;
  #pragma unroll
  for (int i=0;i<16;i+=4){
    float4 v = *(const float4*)(src + (size_t)(by+r)*C + bx + c0 + i);
    tl[r][c0+i]=v.x; tl[r][c0+i+1]=v.y; tl[r][c0+i+2]=v.z; tl[r][c0+i+3]=v.w;
  }
  __syncthreads();
  u16 tmp[16];
  #pragma unroll
  for (int i=0;i<16;i++) tmp[i] = f2b(tl[c0+i][r]);
  *(uint4*)(dst + (size_t)(bx+r)*R + by + c0)     = *(uint4*)&tmp[0];
  *(uint4*)(dst + (size_t)(bx+r)*R + by + c0 + 8) = *(uint4*)&tmp[8];
}

// ---------- transpose + split: fp32 [256][256] -> hi/lo bf16 [256][256] ----------
__global__ __launch_bounds__(256) void k_transp_split(const float* __restrict__ S, u16* __restrict__ DH, u16* __restrict__ DL){
  __shared__ float tl[64][65];
  int bx=blockIdx.x*64, by=blockIdx.y*64;
  int tid=threadIdx.x, r=tid>>2, c0=(tid&3)*16;
  #pragma unroll
  for (int i=0;i<16;i+=4){
    float4 v = *(const float4*)(S + (size_t)(by+r)*256 + bx + c0 + i);
    tl[r][c0+i]=v.x; tl[r][c0+i+1]=v.y; tl[r][c0+i+2]=v.z; tl[r][c0+i+3]=v.w;
  }
  __syncthreads();
  u16 th[16], tll[16];
  #pragma unroll
  for (int i=0;i<16;i++){
    float v = tl[c0+i][r];
    th[i]=f2b(v); tll[i]=f2b(v - b2f(th[i]));
  }
  *(uint4*)(DH + (size_t)(bx+r)*256 + by + c0)     = *(uint4*)&th[0];
  *(uint4*)(DH + (size_t)(bx+r)*256 + by + c0 + 8) = *(uint4*)&th[8];
  *(uint4*)(DL + (size_t)(bx+r)*256 + by + c0)     = *(uint4*)&tll[0];
  *(uint4*)(DL + (size_t)(bx+r)*256 + by + c0 + 8) = *(uint4*)&tll[8];
}

// ---------- pos_query ----------
__global__ __launch_bounds__(256) void k_posq(const float* __restrict__ x, const int* __restrict__ mask,
                                              float* __restrict__ pq, float* __restrict__ cnt){
  int b = blockIdx.x, chunk = blockIdx.y;
  int d = threadIdx.x;
  int n0 = chunk*64;
  float acc = 0.f; float c = 0.f;
  for (int i=0;i<64;i++){
    int n = n0+i;
    if (mask[b*NN+n]==1){ acc += x[((size_t)(b*NN+n))*DD + d]; c += 1.f; }
  }
  atomicAdd(&pq[b*DD+d], acc);
  if (d==0) atomicAdd(&cnt[b], c);
}

__global__ __launch_bounds__(256) void k_sq(const float* __restrict__ pq, const float* __restrict__ cnt,
                                            const float* __restrict__ Wq, float* __restrict__ sq){
  int b = blockIdx.x, e = threadIdx.x;
  float inv = 1.f / fmaxf(cnt[b], 1.f);
  float acc=0.f;
  for (int d0=0; d0<DD; d0++) acc += (pq[b*DD+d0]*inv) * Wq[d0*DD+e];
  sq[b*DD+e] = acc;
}

__global__ __launch_bounds__(256) void k_simsel(const float* __restrict__ y, const float* __restrict__ sq,
                                                float* __restrict__ simOut, u8* __restrict__ sel8){
  int r = blockIdx.x*4 + (threadIdx.x>>6);
  int lane = threadIdx.x & 63;
  int b = r>>10;
  float4 yv = *(const float4*)(y + (size_t)r*DD + lane*4);
  float4 qv = *(const float4*)(sq + b*DD + lane*4);
  float p = yv.x*qv.x + yv.y*qv.y + yv.z*qv.z + yv.w*qv.w;
  p = wredsum(p);
  if (lane==0){
    float s = p * 0.0625f;
    float sim = 1.f/(1.f+expf(-s));
    simOut[r] = sim;
    sel8[r] = (sim > 0.97f) ? 1 : 0;
  }
}

// ---------- no-LDS MFMA GEMM: out[8192, OC] = A[8192,KK] @ BT[OC,KK]^T ----------
// EPI: 0 = store fp32, 1 = fp32 +=, 2 = final out=x+gamma*acc fp32, 3 = bf16 store
template<int EPI>
__global__ __launch_bounds__(256) void k_mgemm(const u16* __restrict__ A, const u16* __restrict__ BT,
    int KK, int ldB, float* __restrict__ C, const float* __restrict__ Xres,
    const float* __restrict__ gamma, u16* __restrict__ O){
  int tid=threadIdx.x, w=tid>>6, lane=tid&63, L=lane&15, q=lane>>4;
  int OC = gridDim.x<<6;
  int colBase=blockIdx.x<<6, rowBase=blockIdx.y<<6;
  const u16* ap = A + (size_t)(rowBase + w*16 + L)*KK + q*8;
  const u16* bp = BT + (size_t)(colBase + L)*ldB + q*8;
  size_t bs = (size_t)16*ldB;
  f4v z4={0.f,0.f,0.f,0.f};
  f4v acc[4]={z4,z4,z4,z4};
  s8v a0 = *(const s8v*)ap;
  s8v b0 = *(const s8v*)bp;
  s8v b1 = *(const s8v*)(bp + bs);
  s8v b2 = *(const s8v*)(bp + 2*bs);
  s8v b3 = *(const s8v*)(bp + 3*bs);
  for (int k0=32;k0<KK;k0+=32){
    s8v an  = *(const s8v*)(ap + k0);
    s8v bn0 = *(const s8v*)(bp + k0);
    s8v bn1 = *(const s8v*)(bp + bs + k0);
    s8v bn2 = *(const s8v*)(bp + 2*bs + k0);
    s8v bn3 = *(const s8v*)(bp + 3*bs + k0);
    acc[0]=MFMA(a0,b0,acc[0]); acc[1]=MFMA(a0,b1,acc[1]);
    acc[2]=MFMA(a0,b2,acc[2]); acc[3]=MFMA(a0,b3,acc[3]);
    a0=an; b0=bn0; b1=bn1; b2=bn2; b3=bn3;
  }
  acc[0]=MFMA(a0,b0,acc[0]); acc[1]=MFMA(a0,b1,acc[1]);
  acc[2]=MFMA(a0,b2,acc[2]); acc[3]=MFMA(a0,b3,acc[3]);
  #pragma unroll
  for (int t=0;t<4;t++){
    int col = colBase + t*16 + L;
    #pragma unroll
    for (int reg=0;reg<4;reg++){
      int row = rowBase + w*16 + q*4 + reg;
      size_t off = (size_t)row*OC + col;
      float v = acc[t][reg];
      if constexpr (EPI==0){ C[off] = v; }
      else if constexpr (EPI==1){ C[off] += v; }
      else if constexpr (EPI==2){ C[off] = flushf(Xres[off] + gamma[col]*v); }
      else { O[off] = f2b(v); }
    }
  }
}

// ---------- split (3-term) MFMA GEMM: KK=256, OC=256 ----------
// EPI: 0 = store fp32 C, 4 = store split pair (Oh, Ol)
template<int EPI>
__global__ __launch_bounds__(256) void k_msgemm(const u16* __restrict__ Ah, const u16* __restrict__ Al,
    const u16* __restrict__ Bh, const u16* __restrict__ Bl,
    float* __restrict__ C, u16* __restrict__ Oh, u16* __restrict__ Ol){
  int tid=threadIdx.x, w=tid>>6, lane=tid&63, L=lane&15, q=lane>>4;
  int colBase=blockIdx.x<<6, rowBase=blockIdx.y<<6;
  const u16* ahp = Ah + (size_t)(rowBase + w*16 + L)*256 + q*8;
  const u16* alp = Al + (size_t)(rowBase + w*16 + L)*256 + q*8;
  const u16* bhp = Bh + (size_t)(colBase + L)*256 + q*8;
  const u16* blp = Bl + (size_t)(colBase + L)*256 + q*8;
  f4v z4={0.f,0.f,0.f,0.f};
  f4v acc[4]={z4,z4,z4,z4};
  for (int k0=0;k0<256;k0+=32){
    s8v ah=*(const s8v*)(ahp+k0), al=*(const s8v*)(alp+k0);
    #pragma unroll
    for (int t=0;t<4;t++){
      s8v bh=*(const s8v*)(bhp + (size_t)t*16*256 + k0);
      s8v bl=*(const s8v*)(blp + (size_t)t*16*256 + k0);
      acc[t]=MFMA(ah,bh,acc[t]);
      acc[t]=MFMA(ah,bl,acc[t]);
      acc[t]=MFMA(al,bh,acc[t]);
    }
  }
  #pragma unroll
  for (int t=0;t<4;t++){
    int col = colBase + t*16 + L;
    #pragma unroll
    for (int reg=0;reg<4;reg++){
      int row = rowBase + w*16 + q*4 + reg;
      size_t off = (size_t)row*256 + col;
      float v = acc[t][reg];
      if constexpr (EPI==0){ C[off] = v; }
      else { u16 h = f2b(v); Oh[off]=h; Ol[off]=f2b(v - b2f(h)); }
    }
  }
}

// ---------- split MFMA gram + bitpack: conn[(b*N+n)*32 + m/32] ----------
__global__ __launch_bounds__(256) void k_mconnect(const u16* __restrict__ fah, const u16* __restrict__ fal,
    const u8* __restrict__ sel8, u32* __restrict__ conn){
  __shared__ u8 sg[64][64];
  int tid=threadIdx.x, w=tid>>6, lane=tid&63, L=lane&15, q=lane>>4;
  int b=blockIdx.z;
  int mBase=blockIdx.x*64, nBase=blockIdx.y*64;
  size_t bOff=(size_t)b*NN;
  const u16* ahp = fah + (bOff + nBase + w*16 + L)*256 + q*8;
  const u16* alp = fal + (bOff + nBase + w*16 + L)*256 + q*8;
  const u16* bhp = fah + (bOff + mBase + L)*256 + q*8;
  const u16* blp = fal + (bOff + mBase + L)*256 + q*8;
  f4v z4={0.f,0.f,0.f,0.f};
  f4v acc[4]={z4,z4,z4,z4};
  for (int k0=0;k0<256;k0+=32){
    s8v ah=*(const s8v*)(ahp+k0), al=*(const s8v*)(alp+k0);
    #pragma unroll
    for (int t=0;t<4;t++){
      s8v bh=*(const s8v*)(bhp + (size_t)t*16*256 + k0);
      s8v bl=*(const s8v*)(blp + (size_t)t*16*256 + k0);
      acc[t]=MFMA(ah,bh,acc[t]);
      acc[t]=MFMA(ah,bl,acc[t]);
      acc[t]=MFMA(al,bh,acc[t]);
    }
  }
  #pragma unroll
  for (int t=0;t<4;t++)
    #pragma unroll
    for (int reg=0;reg<4;reg++)
      sg[w*16 + q*4 + reg][t*16 + L] = acc[t][reg] > 0.f;
  __syncthreads();
  if (tid<128){
    int row=tid>>1, ww=tid&1;
    int nG = nBase+row;
    u32 word=0;
    if (sel8[b*NN + nG]){
      for (int j=0;j<32;j++){
        int m = mBase + ww*32 + j;
        if (sg[row][ww*32+j] && sel8[b*NN+m]) word |= (1u<<j);
      }
    }
    conn[((size_t)b*NN + nG)*32 + (mBase>>5) + ww] = word;
  }
}

// ---------- s1/s2 = V @ a1, V @ a2 ; grid (BN/4, heads) ----------
template<typename VT>
__global__ __launch_bounds__(256) void k_s1s2(const VT* __restrict__ V, int ldV, int colStep,
    const float* __restrict__ a1, const float* __restrict__ a2, int aStep,
    float* __restrict__ s1a, float* __restrict__ s2a){
  int h = blockIdx.y;
  int r = blockIdx.x*4 + (threadIdx.x>>6);
  int lane = threadIdx.x&63;
  float4 v;
  if constexpr (sizeof(VT)==2) v = ld4bf((const u16*)V + (size_t)r*ldV + h*colStep + lane*4);
  else                         v = *(const float4*)((const float*)V + (size_t)r*ldV + h*colStep + lane*4);
  const float* a1p = a1 + h*aStep; const float* a2p = a2 + h*aStep;
  float4 w1 = *(const float4*)(a1p+lane*4), w2 = *(const float4*)(a2p+lane*4);
  float d1 = v.x*w1.x+v.y*w1.y+v.z*w1.z+v.w*w1.w;
  float d2 = v.x*w2.x+v.y*w2.y+v.z*w2.z+v.w*w2.w;
  d1=wredsum(d1); d2=wredsum(d2);
  if (lane==0){ s1a[h*BN+r]=d1; s2a[h*BN+r]=d2; }
}

// ---------- GAT row softmax stats; grid (BN/4, heads) ----------
__global__ __launch_bounds__(256) void k_rowstats(const float* __restrict__ s1a, const float* __restrict__ s2a,
    const u32* __restrict__ conn, float* __restrict__ rmxa, float* __restrict__ rina){
  int h = blockIdx.y;
  int r = blockIdx.x*4 + (threadIdx.x>>6);
  int lane = threadIdx.x&63;
  int b = r>>10;
  float sr = s1a[h*BN+r];
  const float* s2p = s2a + h*BN + b*NN;
  float e[16];
  float mx = -3.0e38f;
  #pragma unroll
  for (int t=0;t<16;t++){
    int m = lane + t*64;
    u32 w = conn[(size_t)r*32 + (m>>5)];
    float ev;
    if ((w>>(m&31))&1u){ ev = leakyf(sr + s2p[m]); }
    else ev = -9.0e15f;
    e[t]=ev; mx = fmaxf(mx,ev);
  }
  mx = wredmax(mx);
  float sm=0.f;
  #pragma unroll
  for (int t=0;t<16;t++) sm += exp0(e[t]-mx);
  sm = wredsum(sm);
  if (lane==0){ rmxa[h*BN+r]=mx; rina[h*BN+r]=1.f/sm; }
}

// ---------- MFMA GAT attention: Out = elu(P @ V); grid (4, 128, heads) ----------
template<typename VT>
__global__ __launch_bounds__(256) void k_mattn(const float* __restrict__ s1a, const float* __restrict__ s2a,
    const float* __restrict__ rmxa, const float* __restrict__ rina, const u32* __restrict__ conn,
    const VT* __restrict__ V, int vStride, u16* __restrict__ Out, int oStride, int headMul){
  __shared__ __align__(16) u16 Vt[64][40];
  int tid=threadIdx.x, w=tid>>6, lane=tid&63, L=lane&15, q=lane>>4;
  int colBase=blockIdx.x*64, rowBase=blockIdx.y*64;
  int h=blockIdx.z; int hOff=h*headMul; int sOff=h*BN;
  int b=rowBase>>10;
  size_t bOff=(size_t)b*NN;
  int r = rowBase + w*16 + L;
  float s1v=s1a[sOff+r], rmv=rmxa[sOff+r], riv=rina[sOff+r];
  const float* s2p = s2a + sOff + bOff;
  f4v z4={0.f,0.f,0.f,0.f};
  f4v acc[4]={z4,z4,z4,z4};
  int sm_=tid&31, sd0=(tid>>5)*8;
  for (int k0=0;k0<NN;k0+=32){
    __syncthreads();
    {
      const VT* vp = V + (bOff + k0 + sm_)*(size_t)vStride + hOff + colBase + sd0;
      u16 tmp[8];
      if constexpr (sizeof(VT)==2){
        *(uint4*)&tmp[0] = *(const uint4*)vp;
      } else {
        float vv[8]; load8((const float*)vp, vv);
        #pragma unroll
        for (int i=0;i<8;i++) tmp[i]=f2b(vv[i]);
      }
      #pragma unroll
      for (int i=0;i<8;i++) Vt[sd0+i][sm_] = tmp[i];
    }
    u32 cw = conn[(size_t)r*32 + (k0>>5)];
    s8v pf;
    #pragma unroll
    for (int j=0;j<8;j++){
      int m = k0 + q*8 + j;
      float ev = ((cw>>(q*8+j))&1u) ? leakyf(s1v + s2p[m]) : -9.0e15f;
      pf[j] = (short)f2b(exp0(ev - rmv)*riv);
    }
    __syncthreads();
    #pragma unroll
    for (int t=0;t<4;t++){
      s8v vf = *(const s8v*)&Vt[t*16 + L][q*8];
      acc[t] = MFMA(pf, vf, acc[t]);
    }
  }
  #pragma unroll
  for (int t=0;t<4;t++){
    int col = hOff + colBase + t*16 + L;
    #pragma unroll
    for (int reg=0;reg<4;reg++){
      int row = rowBase + w*16 + q*4 + reg;
      Out[(size_t)row*oStride + col] = f2b(eluf(acc[t][reg]));
    }
  }
}

// ---------- LayerNorms ----------
__global__ __launch_bounds__(256) void k_ln_x(const float* __restrict__ x, const float* __restrict__ g,
                                              const float* __restrict__ bb, u16* __restrict__ out){
  int r = blockIdx.x*4 + (threadIdx.x>>6);
  int lane=threadIdx.x&63;
  float4 v = *(const float4*)(x + (size_t)r*DD + lane*4);
  float s = v.x+v.y+v.z+v.w;
  float s2 = v.x*v.x+v.y*v.y+v.z*v.z+v.w*v.w;
  s = wredsum(s); s2 = wredsum(s2);
  float mean = s*(1.f/256.f);
  float var = s2*(1.f/256.f) - mean*mean;
  float rstd = rsqrtf(var + 1e-5f);
  float4 gv = *(const float4*)(g+lane*4), bv = *(const float4*)(bb+lane*4);
  u16 t[4];
  t[0]=f2b((v.x-mean)*rstd*gv.x+bv.x); t[1]=f2b((v.y-mean)*rstd*gv.y+bv.y);
  t[2]=f2b((v.z-mean)*rstd*gv.z+bv.z); t[3]=f2b((v.w-mean)*rstd*gv.w+bv.w);
  *(uint2*)(out + (size_t)r*DD + lane*4) = *(uint2*)&t[0];
}

__global__ __launch_bounds__(256) void k_ln_kv(const u16* __restrict__ gout, const float* __restrict__ pe,
    const u8* __restrict__ sel8, const float* __restrict__ g, const float* __restrict__ bb,
    u16* __restrict__ out){
  int r = blockIdx.x*4 + (threadIdx.x>>6);
  int lane=threadIdx.x&63;
  int n = r & 1023;
  float4 v = make_float4(0.f,0.f,0.f,0.f);
  if (sel8[r]){
    float4 gv = ld4bf(gout + (size_t)r*DD + lane*4);
    float4 pv = *(const float4*)(pe + (size_t)n*DD + lane*4);
    v = make_float4(gv.x+pv.x, gv.y+pv.y, gv.z+pv.z, gv.w+pv.w);
  }
  float s = v.x+v.y+v.z+v.w;
  float s2 = v.x*v.x+v.y*v.y+v.z*v.z+v.w*v.w;
  s = wredsum(s); s2 = wredsum(s2);
  float mean = s*(1.f/256.f);
  float var = s2*(1.f/256.f) - mean*mean;
  float rstd = rsqrtf(var + 1e-5f);
  float4 gv = *(const float4*)(g+lane*4), bv = *(const float4*)(bb+lane*4);
  u16 t[4];
  t[0]=f2b((v.x-mean)*rstd*gv.x+bv.x); t[1]=f2b((v.y-mean)*rstd*gv.y+bv.y);
  t[2]=f2b((v.z-mean)*rstd*gv.z+bv.z); t[3]=f2b((v.w-mean)*rstd*gv.w+bv.w);
  *(uint2*)(out + (size_t)r*DD + lane*4) = *(uint2*)&t[0];
}

// ---------- MFMA CA stats ----------
__global__ __launch_bounds__(256) void k_mca_stats(const u16* __restrict__ q, const u16* __restrict__ k,
    const u8* __restrict__ sel8, float* __restrict__ cmax, float* __restrict__ cinv){
  __shared__ __align__(16) u16 Qls[64][72];
  __shared__ __align__(16) u16 Kls[64][72];
  __shared__ float cw4[4];
  int tid=threadIdx.x;
  int w = tid>>6, lane = tid&63, L = lane&15, qd = lane>>4;
  int b=blockIdx.z, h=blockIdx.y, rowBase=blockIdx.x*64;
  size_t bOff = (size_t)b*NN;
  {
    float c = 0.f;
    #pragma unroll
    for (int i=0;i<4;i++) c += sel8[b*NN + tid*4 + i] ? 0.f : 1.f;
    c = wredsum(c);
    if (lane==0) cw4[w]=c;
  }
  {
    int r=tid>>2, c0=(tid&3)*16;
    size_t base = (bOff + rowBase + r)*(size_t)DD + h*64 + c0;
    *(uint4*)&Qls[r][c0]   = *(const uint4*)(q + base);
    *(uint4*)&Qls[r][c0+8] = *(const uint4*)(q + base + 8);
  }
  float um[4], us[4];
  #pragma unroll
  for (int i=0;i<4;i++){ um[i]=-3.0e38f; us[i]=0.f; }
  for (int m0=0;m0<NN;m0+=64){
    __syncthreads();
    {
      int r=tid>>2, c0=(tid&3)*16;
      size_t base = (bOff + m0 + r)*(size_t)DD + h*64 + c0;
      *(uint4*)&Kls[r][c0]   = *(const uint4*)(k + base);
      *(uint4*)&Kls[r][c0+8] = *(const uint4*)(k + base + 8);
    }
    __syncthreads();
    f4v zero = {0.f,0.f,0.f,0.f};
    f4v sa[4] = {zero,zero,zero,zero};
    #pragma unroll
    for (int kc=0;kc<64;kc+=32){
      s8v af = *(const s8v*)&Qls[w*16 + L][kc + qd*8];
      #pragma unroll
      for (int t=0;t<4;t++){
        s8v bfr = *(const s8v*)&Kls[t*16 + L][kc + qd*8];
        sa[t] = MFMA(af, bfr, sa[t]);
      }
    }
    #pragma unroll
    for (int t=0;t<4;t++){
      int m = m0 + t*16 + L;
      if (sel8[b*NN+m]){
        #pragma unroll
        for (int reg=0;reg<4;reg++){
          float val = sa[t][reg]*0.125f;
          float nm = fmaxf(um[reg], val);
          us[reg] = us[reg]*exp0(um[reg]-nm) + exp0(val-nm);
          um[reg] = nm;
        }
      }
    }
  }
  #pragma unroll
  for (int off=1;off<16;off<<=1){
    #pragma unroll
    for (int reg=0;reg<4;reg++){
      float om = __shfl_xor(um[reg], off);
      float os = __shfl_xor(us[reg], off);
      float nm = fmaxf(um[reg], om);
      us[reg] = us[reg]*exp0(um[reg]-nm) + os*exp0(om-nm);
      um[reg] = nm;
    }
  }
  __syncthreads();
  float cn = cw4[0]+cw4[1]+cw4[2]+cw4[3];
  if (L==0){
    #pragma unroll
    for (int reg=0;reg<4;reg++){
      int row = rowBase + w*16 + qd*4 + reg;
      float M = um[reg];
      if (cn>0.f) M = fmaxf(M, -1.0e9f);
      float S = cn*exp0(-1.0e9f - M) + us[reg]*exp0(um[reg]-M);
      size_t o = ((size_t)b*HC+h)*NN + row;
      cmax[o]=M; cinv[o]=1.f/S;
    }
  }
}

// ---------- MFMA CA attention ----------
__global__ __launch_bounds__(256) void k_mca_av(const u16* __restrict__ q, const u16* __restrict__ k,
    const u16* __restrict__ v, const u8* __restrict__ sel8,
    const float* __restrict__ cmax, const float* __restrict__ cinv, u16* __restrict__ O){
  __shared__ __align__(16) u16 Qls[64][72];
  __shared__ __align__(16) u16 KP[64][72];
  __shared__ __align__(16) u16 Vt[64][72];
  int tid=threadIdx.x;
  int w = tid>>6, lane = tid&63, L = lane&15, qd = lane>>4;
  int b=blockIdx.z, h=blockIdx.y, rowBase=blockIdx.x*64;
  size_t bOff = (size_t)b*NN;
  {
    int r=tid>>2, c0=(tid&3)*16;
    size_t base = (bOff + rowBase + r)*(size_t)DD + h*64 + c0;
    *(uint4*)&Qls[r][c0]   = *(const uint4*)(q + base);
    *(uint4*)&Qls[r][c0+8] = *(const uint4*)(q + base + 8);
  }
  float rm[4], ri[4];
  #pragma unroll
  for (int reg=0;reg<4;reg++){
    size_t o = ((size_t)b*HC+h)*NN + rowBase + w*16 + qd*4 + reg;
    rm[reg]=cmax[o]; ri[reg]=cinv[o];
  }
  f4v zero = {0.f,0.f,0.f,0.f};
  f4v acc[4] = {zero,zero,zero,zero};
  int svm = tid&63, svd0 = (tid>>6)*16;
  for (int m0=0;m0<NN;m0+=64){
    __syncthreads();
    {
      int r=tid>>2, c0=(tid&3)*16;
      size_t base = (bOff + m0 + r)*(size_t)DD + h*64 + c0;
      *(uint4*)&KP[r][c0]   = *(const uint4*)(k + base);
      *(uint4*)&KP[r][c0+8] = *(const uint4*)(k + base + 8);
      size_t vb_ = (bOff + m0 + svm)*(size_t)DD + h*64 + svd0;
      uint4 u0 = *(const uint4*)(v + vb_);
      uint4 u1 = *(const uint4*)(v + vb_ + 8);
      u16 tmp[16];
      *(uint4*)&tmp[0]=u0; *(uint4*)&tmp[8]=u1;
      #pragma unroll
      for (int i=0;i<16;i++) Vt[svd0+i][svm] = tmp[i];
    }
    __syncthreads();
    f4v sa[4] = {zero,zero,zero,zero};
    #pragma unroll
    for (int kc=0;kc<64;kc+=32){
      s8v af = *(const s8v*)&Qls[w*16 + L][kc + qd*8];
      #pragma unroll
      for (int t=0;t<4;t++){
        s8v bfr = *(const s8v*)&KP[t*16 + L][kc + qd*8];
        sa[t] = MFMA(af, bfr, sa[t]);
      }
    }
    __syncthreads();
    #pragma unroll
    for (int t=0;t<4;t++){
      int m = m0 + t*16 + L;
      bool sl = sel8[b*NN+m];
      #pragma unroll
      for (int reg=0;reg<4;reg++){
        float val = sl ? sa[t][reg]*0.125f : -1.0e9f;
        KP[w*16 + qd*4 + reg][t*16 + L] = f2b(exp0(val - rm[reg])*ri[reg]);
      }
    }
    __syncthreads();
    #pragma unroll
    for (int mc=0;mc<64;mc+=32){
      s8v pf = *(const s8v*)&KP[w*16 + L][mc + qd*8];
      #pragma unroll
      for (int t=0;t<4;t++){
        s8v vf = *(const s8v*)&Vt[t*16 + L][mc + qd*8];
        acc[t] = MFMA(pf, vf, acc[t]);
      }
    }
  }
  #pragma unroll
  for (int t=0;t<4;t++){
    int col = h*64 + t*16 + L;
    #pragma unroll
    for (int reg=0;reg<4;reg++){
      int row = rowBase + w*16 + qd*4 + reg;
      O[(bOff + row)*(size_t)DD + col] = f2b(acc[t][reg]);
    }
  }
}

extern "C" void kernel_launch(void* const* d_in, const int* in_sizes, int n_in,
                              void* d_out, int out_size, void* d_ws, size_t ws_size,
                              hipStream_t stream) {
  (void)in_sizes; (void)n_in; (void)out_size;
  const float* x      = (const float*)d_in[0];
  const int*   mask   = (const int*  )d_in[1];
  const float* pe     = (const float*)d_in[2];
  const float* sim_Wx = (const float*)d_in[3];
  const float* sim_Wq = (const float*)d_in[4];
  const float* adj_W  = (const float*)d_in[5];
  const float* gat_W  = (const float*)d_in[6];
  const float* gat_a1 = (const float*)d_in[7];
  const float* gat_a2 = (const float*)d_in[8];
  const float* gat_Wo = (const float*)d_in[9];
  const float* gat_ao1= (const float*)d_in[10];
  const float* gat_ao2= (const float*)d_in[11];
  const float* ln3_g  = (const float*)d_in[12];
  const float* ln3_b  = (const float*)d_in[13];
  const float* ln4_g  = (const float*)d_in[14];
  const float* ln4_b  = (const float*)d_in[15];
  const float* ca_Wq  = (const float*)d_in[16];
  const float* ca_Wk  = (const float*)d_in[17];
  const float* ca_Wv  = (const float*)d_in[18];
  const float* ca_Wp  = (const float*)d_in[19];
  const float* gamma  = (const float*)d_in[20];
  float* out    = (float*)d_out;
  float* simOut = out + (size_t)BN*DD;

  const size_t MB = 1024*1024;
  bool big = ws_size >= 98*MB;
  char* W = (char*)d_ws;
  float* pq   = (float*)W;                     // 2048
  float* cnt  = pq + 2048;                     // 16
  float* sq   = cnt + 16;                      // 2048
  float* s1a  = (float*)(W + 64*1024);         // 8*8192
  float* s2a  = (float*)(W + 320*1024);
  float* rmxa = (float*)(W + 576*1024);
  float* rina = (float*)(W + 832*1024);
  float* cam  = (float*)(W + 1088*1024);
  float* civ  = (float*)(W + 1216*1024);
  u8*    sel8 = (u8*)(W + 1400*1024);
  u32*   conn = (u32*)(W + 2*MB);              // 1MB
  u16*   WT0  = (u16*)(W + 3*MB);              // gat_W^T  [2048][256] (1MB)
  u16*   WoT  = (u16*)(W + 4*MB);              // gat_Wo^T [256][2048] (1MB)
  u16*   WQT  = (u16*)(W + 5*MB);
  u16*   WKT  = WQT + 65536;
  u16*   WVT  = WKT + 65536;
  u16*   WPT  = WVT + 65536;                   // ends 5.5MB
  u16*   sWxh = (u16*)(W + 5*MB + 512*1024);
  u16*   sWxl = sWxh + 65536;
  u16*   aWh  = sWxl + 65536;
  u16*   aWl  = aWh + 65536;                   // ends 6MB
  u16*   xh   = (u16*)(W + 6*MB);              // 4MB
  u16*   xl   = (u16*)(W + 10*MB);             // 4MB
  float* S0   = (float*)(W + 14*MB);           // 8MB fp32: y -> Who
  u16*   fah  = (u16*)(W + 22*MB);             // 4MB
  u16*   fal  = (u16*)(W + 26*MB);             // 4MB
  u16*   T2   = (u16*)(W + 30*MB);             // 4MB: gout -> qb (fallback)

  // prep
  k_split<<<BN*DD/2048,256,0,stream>>>(x, xh, xl);
  k_transpose<<<dim3(4,4,HG),256,0,stream>>>(gat_W, WT0, 256, 65536);
  k_transpose<<<dim3(4,32,1),256,0,stream>>>(gat_Wo, WoT, 2048, 0);
  k_transpose<<<dim3(4,4,1),256,0,stream>>>(ca_Wq, WQT, 256, 0);
  k_transpose<<<dim3(4,4,1),256,0,stream>>>(ca_Wk, WKT, 256, 0);
  k_transpose<<<dim3(4,4,1),256,0,stream>>>(ca_Wv, WVT, 256, 0);
  k_transpose<<<dim3(4,4,1),256,0,stream>>>(ca_Wp, WPT, 256, 0);
  k_transp_split<<<dim3(4,4,1),256,0,stream>>>(sim_Wx, sWxh, sWxl);
  k_transp_split<<<dim3(4,4,1),256,0,stream>>>(adj_W, aWh, aWl);

  hipMemsetAsync(pq, 0, (2048+16)*sizeof(float), stream);
  k_posq<<<dim3(BB,16),256,0,stream>>>(x, mask, pq, cnt);
  k_sq<<<BB,256,0,stream>>>(pq, cnt, sim_Wq, sq);
  k_msgemm<0><<<dim3(4,128),256,0,stream>>>(xh, xl, sWxh, sWxl, S0, nullptr, nullptr);  // y
  k_simsel<<<BN/4,256,0,stream>>>(S0, sq, simOut, sel8);
  k_msgemm<4><<<dim3(4,128),256,0,stream>>>(xh, xl, aWh, aWl, nullptr, fah, fal);       // fa split
  k_mconnect<<<dim3(16,16,BB),256,0,stream>>>(fah, fal, sel8, conn);

  if (big){
    u16* whcat = (u16*)(W + 34*MB);            // 32MB [8192][2048]
    u16* htcat = (u16*)(W + 66*MB);            // 32MB [8192][2048]
    u16* qx = (u16*)(W + 34*MB);               // CA bufs reuse whcat region after GAT
    u16* kv = (u16*)(W + 38*MB);
    u16* qb = (u16*)(W + 42*MB);
    u16* kb = (u16*)(W + 46*MB);
    u16* vb = (u16*)(W + 50*MB);
    u16* Ob = (u16*)(W + 54*MB);

    k_mgemm<3><<<dim3(32,128),256,0,stream>>>(xh, WT0, 256, 256, nullptr, nullptr, nullptr, whcat); // Wh_cat
    k_s1s2<u16><<<dim3(BN/4,HG),256,0,stream>>>(whcat, 2048, 256, gat_a1, gat_a2, 256, s1a, s2a);
    k_rowstats<<<dim3(BN/4,HG),256,0,stream>>>(s1a, s2a, conn, rmxa, rina);
    k_mattn<u16><<<dim3(4,128,HG),256,0,stream>>>(s1a, s2a, rmxa, rina, conn, whcat, 2048, htcat, 2048, 256);
    k_mgemm<0><<<dim3(4,128),256,0,stream>>>(htcat, WoT, 2048, 2048, S0, nullptr, nullptr, nullptr); // Who fp32
    k_s1s2<float><<<dim3(BN/4,1),256,0,stream>>>(S0, 256, 0, gat_ao1, gat_ao2, 0, s1a, s2a);
    k_rowstats<<<dim3(BN/4,1),256,0,stream>>>(s1a, s2a, conn, rmxa, rina);
    k_mattn<float><<<dim3(4,128,1),256,0,stream>>>(s1a, s2a, rmxa, rina, conn, S0, 256, T2, 256, 0);  // gout

    k_ln_x<<<BN/4,256,0,stream>>>(x, ln3_g, ln3_b, qx);
    k_ln_kv<<<BN/4,256,0,stream>>>(T2, pe, sel8, ln4_g, ln4_b, kv);
    k_mgemm<3><<<dim3(4,128),256,0,stream>>>(qx, WQT, 256, 256, nullptr, nullptr, nullptr, qb);
    k_mgemm<3><<<dim3(4,128),256,0,stream>>>(kv, WKT, 256, 256, nullptr, nullptr, nullptr, kb);
    k_mgemm<3><<<dim3(4,128),256,0,stream>>>(kv, WVT, 256, 256, nullptr, nullptr, nullptr, vb);
    k_mca_stats<<<dim3(16,HC,BB),256,0,stream>>>(qb, kb, sel8, cam, civ);
    k_mca_av<<<dim3(16,HC,BB),256,0,stream>>>(qb, kb, vb, sel8, cam, civ, Ob);
    k_mgemm<2><<<dim3(4,128),256,0,stream>>>(Ob, WPT, 256, 256, out, x, gamma, nullptr);
  } else {
    u16* T0 = fah;                              // fa split dead after k_mconnect
    u16* T1 = fal;
    u16* S0b = (u16*)S0;
    hipMemsetAsync(S0, 0, 8*MB, stream);        // Who = 0
    for (int h=0;h<HG;h++){
      k_mgemm<3><<<dim3(4,128),256,0,stream>>>(xh, WT0 + (size_t)h*65536, 256, 256, nullptr, nullptr, nullptr, T0);
      k_s1s2<u16><<<dim3(BN/4,1),256,0,stream>>>(T0, 256, 0, gat_a1 + h*DD, gat_a2 + h*DD, 0, s1a, s2a);
      k_rowstats<<<dim3(BN/4,1),256,0,stream>>>(s1a, s2a, conn, rmxa, rina);
      k_mattn<u16><<<dim3(4,128,1),256,0,stream>>>(s1a, s2a, rmxa, rina, conn, T0, 256, T1, 256, 0);
      k_mgemm<1><<<dim3(4,128),256,0,stream>>>(T1, WoT + (size_t)h*256, 256, 2048, S0, nullptr, nullptr, nullptr);
    }
    k_s1s2<float><<<dim3(BN/4,1),256,0,stream>>>(S0, 256, 0, gat_ao1, gat_ao2, 0, s1a, s2a);
    k_rowstats<<<dim3(BN/4,1),256,0,stream>>>(s1a, s2a, conn, rmxa, rina);
    k_mattn<float><<<dim3(4,128,1),256,0,stream>>>(s1a, s2a, rmxa, rina, conn, S0, 256, T2, 256, 0); // gout

    k_ln_x<<<BN/4,256,0,stream>>>(x, ln3_g, ln3_b, T1);                       // qx
    k_ln_kv<<<BN/4,256,0,stream>>>(T2, pe, sel8, ln4_g, ln4_b, T0);           // kv
    k_mgemm<3><<<dim3(4,128),256,0,stream>>>(T1, WQT, 256, 256, nullptr, nullptr, nullptr, T2);  // qb
    k_mgemm<3><<<dim3(4,128),256,0,stream>>>(T0, WKT, 256, 256, nullptr, nullptr, nullptr, T1);  // kb
    k_mgemm<3><<<dim3(4,128),256,0,stream>>>(T0, WVT, 256, 256, nullptr, nullptr, nullptr, S0b); // vb
    k_mca_stats<<<dim3(16,HC,BB),256,0,stream>>>(T2, T1, sel8, cam, civ);
    k_mca_av<<<dim3(16,HC,BB),256,0,stream>>>(T2, T1, S0b, sel8, cam, civ, T0);                  // Ob
    k_mgemm<2><<<dim3(4,128),256,0,stream>>>(T0, WPT, 256, 256, out, x, gamma, nullptr);
  }
}

// Round 8
// 928.951 us; speedup vs baseline: 1.9058x; 1.0060x over previous
//
#include <hip/hip_runtime.h>
#include <hip/hip_bf16.h>

// GATFusionBlockPosOnly: B=8, N=1024, D=256, 8 GAT heads, 4 CA heads.
// Round 8: GAT attention overhaul.
//  - k_mattn2: full-width (256-col) blocks, P built ONCE per chunk (was 4x),
//    online row-sum with 1/sum applied in epilogue, row-max via monotone-leaky
//    identity rmx = leaky(s1 + max_conn s2)  -> k_rowstats (67M exps) deleted,
//    replaced by cheap k_rowmax (bit-test+max).
//  - Everything else identical to R7 (934 us, absmax 0.094).

#define BB 8
#define NN 1024
#define DD 256
#define HG 8
#define HC 4
#define BN (BB*NN)

typedef unsigned short u16;
typedef unsigned int u32;
typedef unsigned char u8;
typedef __attribute__((ext_vector_type(8))) short s8v;   // 8 bf16
typedef __attribute__((ext_vector_type(4))) float f4v;   // 4 fp32 acc
#define MFMA(a,b,c) __builtin_amdgcn_mfma_f32_16x16x32_bf16((a),(b),(c),0,0,0)

__device__ __forceinline__ u16 f2b(float x){
  union{ float f; unsigned u; } a; a.f = x;
  unsigned r = a.u + 0x7fff + ((a.u>>16)&1);
  return (u16)(r>>16);
}
__device__ __forceinline__ float b2f(u16 b){ return __uint_as_float(((unsigned)b)<<16); }
__device__ __forceinline__ float4 ld4bf(const u16* p){
  uint2 u = *(const uint2*)p;
  float4 r;
  r.x=__uint_as_float(u.x<<16); r.y=__uint_as_float(u.x&0xffff0000u);
  r.z=__uint_as_float(u.y<<16); r.w=__uint_as_float(u.y&0xffff0000u);
  return r;
}
__device__ __forceinline__ void load8(const float* p, float* v){
  float4 a=*(const float4*)p, b=*(const float4*)(p+4);
  v[0]=a.x;v[1]=a.y;v[2]=a.z;v[3]=a.w;v[4]=b.x;v[5]=b.y;v[6]=b.z;v[7]=b.w;
}
__device__ __forceinline__ float wredsum(float v){
  #pragma unroll
  for(int o=32;o>0;o>>=1) v += __shfl_xor(v,o);
  return v;
}
__device__ __forceinline__ float wredmax(float v){
  #pragma unroll
  for(int o=32;o>0;o>>=1) v = fmaxf(v,__shfl_xor(v,o));
  return v;
}
__device__ __forceinline__ float eluf(float x){ return x>0.f ? x : expm1f(x); }
__device__ __forceinline__ float leakyf(float z){ return z>=0.f ? z : 0.2f*z; }
__device__ __forceinline__ float exp0(float a){ return expf(fminf(a, 0.f)); }
__device__ __forceinline__ float flushf(float v){ return (fabsf(v) < 1.0e30f) ? v : 0.f; }

// ---------- fp32 -> (hi,lo) bf16 split ----------
__global__ __launch_bounds__(256) void k_split(const float* __restrict__ X, u16* __restrict__ H, u16* __restrict__ Lo){
  size_t i = ((size_t)blockIdx.x*256 + threadIdx.x)*8;
  float v[8]; load8(X+i, v);
  u16 hh[8], ll[8];
  #pragma unroll
  for (int j=0;j<8;j++){ hh[j]=f2b(v[j]); ll[j]=f2b(v[j]-b2f(hh[j])); }
  *(uint4*)(H+i)=*(uint4*)&hh[0];
  *(uint4*)(Lo+i)=*(uint4*)&ll[0];
}

// ---------- transpose fp32 [R][C] -> bf16 [C][R]; grid (C/64, R/64, slices) ----------
__global__ __launch_bounds__(256) void k_transpose(const float* __restrict__ S, u16* __restrict__ D,
                                                   int R, int sliceElems){
  __shared__ float tl[64][65];
  const float* src = S + (size_t)blockIdx.z*sliceElems;
  u16* dst = D + (size_t)blockIdx.z*sliceElems;
  int C = gridDim.x*64;
  int bx=blockIdx.x*64, by=blockIdx.y*64;
  int tid=threadIdx.x, r=tid>>2, c0=(tid&3)*16;
  #pragma unroll
  for (int i=0;i<16;i+=4){
    float4 v = *(const float4*)(src + (size_t)(by+r)*C + bx + c0 + i);
    tl[r][c0+i]=v.x; tl[r][c0+i+1]=v.y; tl[r][c0+i+2]=v.z; tl[r][c0+i+3]=v.w;
  }
  __syncthreads();
  u16 tmp[16];
  #pragma unroll
  for (int i=0;i<16;i++) tmp[i] = f2b(tl[c0+i][r]);
  *(uint4*)(dst + (size_t)(bx+r)*R + by + c0)     = *(uint4*)&tmp[0];
  *(uint4*)(dst + (size_t)(bx+r)*R + by + c0 + 8) = *(uint4*)&tmp[8];
}

// ---------- transpose + split: fp32 [256][256] -> hi/lo bf16 [256][256] ----------
__global__ __launch_bounds__(256) void k_transp_split(const float* __restrict__ S, u16* __restrict__ DH, u16* __restrict__ DL){
  __shared__ float tl[64][65];
  int bx=blockIdx.x*64, by=blockIdx.y*64;
  int tid=threadIdx.x, r=tid>>2, c0=(tid&3)*16;
  #pragma unroll
  for (int i=0;i<16;i+=4){
    float4 v = *(const float4*)(S + (size_t)(by+r)*256 + bx + c0 + i);
    tl[r][c0+i]=v.x; tl[r][c0+i+1]=v.y; tl[r][c0+i+2]=v.z; tl[r][c0+i+3]=v.w;
  }
  __syncthreads();
  u16 th[16], tll[16];
  #pragma unroll
  for (int i=0;i<16;i++){
    float v = tl[c0+i][r];
    th[i]=f2b(v); tll[i]=f2b(v - b2f(th[i]));
  }
  *(uint4*)(DH + (size_t)(bx+r)*256 + by + c0)     = *(uint4*)&th[0];
  *(uint4*)(DH + (size_t)(bx+r)*256 + by + c0 + 8) = *(uint4*)&th[8];
  *(uint4*)(DL + (size_t)(bx+r)*256 + by + c0)     = *(uint4*)&tll[0];
  *(uint4*)(DL + (size_t)(bx+r)*256 + by + c0 + 8) = *(uint4*)&tll[8];
}

// ---------- pos_query ----------
__global__ __launch_bounds__(256) void k_posq(const float* __restrict__ x, const int* __restrict__ mask,
                                              float* __restrict__ pq, float* __restrict__ cnt){
  int b = blockIdx.x, chunk = blockIdx.y;
  int d = threadIdx.x;
  int n0 = chunk*64;
  float acc = 0.f; float c = 0.f;
  for (int i=0;i<64;i++){
    int n = n0+i;
    if (mask[b*NN+n]==1){ acc += x[((size_t)(b*NN+n))*DD + d]; c += 1.f; }
  }
  atomicAdd(&pq[b*DD+d], acc);
  if (d==0) atomicAdd(&cnt[b], c);
}

__global__ __launch_bounds__(256) void k_sq(const float* __restrict__ pq, const float* __restrict__ cnt,
                                            const float* __restrict__ Wq, float* __restrict__ sq){
  int b = blockIdx.x, e = threadIdx.x;
  float inv = 1.f / fmaxf(cnt[b], 1.f);
  float acc=0.f;
  for (int d0=0; d0<DD; d0++) acc += (pq[b*DD+d0]*inv) * Wq[d0*DD+e];
  sq[b*DD+e] = acc;
}

__global__ __launch_bounds__(256) void k_simsel(const float* __restrict__ y, const float* __restrict__ sq,
                                                float* __restrict__ simOut, u8* __restrict__ sel8){
  int r = blockIdx.x*4 + (threadIdx.x>>6);
  int lane = threadIdx.x & 63;
  int b = r>>10;
  float4 yv = *(const float4*)(y + (size_t)r*DD + lane*4);
  float4 qv = *(const float4*)(sq + b*DD + lane*4);
  float p = yv.x*qv.x + yv.y*qv.y + yv.z*qv.z + yv.w*qv.w;
  p = wredsum(p);
  if (lane==0){
    float s = p * 0.0625f;
    float sim = 1.f/(1.f+expf(-s));
    simOut[r] = sim;
    sel8[r] = (sim > 0.97f) ? 1 : 0;
  }
}

// ---------- no-LDS MFMA GEMM: out[8192, OC] = A[8192,KK] @ BT[OC,KK]^T ----------
// EPI: 0 = store fp32, 1 = fp32 +=, 2 = final out=x+gamma*acc fp32, 3 = bf16 store
template<int EPI>
__global__ __launch_bounds__(256) void k_mgemm(const u16* __restrict__ A, const u16* __restrict__ BT,
    int KK, int ldB, float* __restrict__ C, const float* __restrict__ Xres,
    const float* __restrict__ gamma, u16* __restrict__ O){
  int tid=threadIdx.x, w=tid>>6, lane=tid&63, L=lane&15, q=lane>>4;
  int OC = gridDim.x<<6;
  int colBase=blockIdx.x<<6, rowBase=blockIdx.y<<6;
  const u16* ap = A + (size_t)(rowBase + w*16 + L)*KK + q*8;
  const u16* bp = BT + (size_t)(colBase + L)*ldB + q*8;
  size_t bs = (size_t)16*ldB;
  f4v z4={0.f,0.f,0.f,0.f};
  f4v acc[4]={z4,z4,z4,z4};
  s8v a0 = *(const s8v*)ap;
  s8v b0 = *(const s8v*)bp;
  s8v b1 = *(const s8v*)(bp + bs);
  s8v b2 = *(const s8v*)(bp + 2*bs);
  s8v b3 = *(const s8v*)(bp + 3*bs);
  for (int k0=32;k0<KK;k0+=32){
    s8v an  = *(const s8v*)(ap + k0);
    s8v bn0 = *(const s8v*)(bp + k0);
    s8v bn1 = *(const s8v*)(bp + bs + k0);
    s8v bn2 = *(const s8v*)(bp + 2*bs + k0);
    s8v bn3 = *(const s8v*)(bp + 3*bs + k0);
    acc[0]=MFMA(a0,b0,acc[0]); acc[1]=MFMA(a0,b1,acc[1]);
    acc[2]=MFMA(a0,b2,acc[2]); acc[3]=MFMA(a0,b3,acc[3]);
    a0=an; b0=bn0; b1=bn1; b2=bn2; b3=bn3;
  }
  acc[0]=MFMA(a0,b0,acc[0]); acc[1]=MFMA(a0,b1,acc[1]);
  acc[2]=MFMA(a0,b2,acc[2]); acc[3]=MFMA(a0,b3,acc[3]);
  #pragma unroll
  for (int t=0;t<4;t++){
    int col = colBase + t*16 + L;
    #pragma unroll
    for (int reg=0;reg<4;reg++){
      int row = rowBase + w*16 + q*4 + reg;
      size_t off = (size_t)row*OC + col;
      float v = acc[t][reg];
      if constexpr (EPI==0){ C[off] = v; }
      else if constexpr (EPI==1){ C[off] += v; }
      else if constexpr (EPI==2){ C[off] = flushf(Xres[off] + gamma[col]*v); }
      else { O[off] = f2b(v); }
    }
  }
}

// ---------- split (3-term) MFMA GEMM: KK=256, OC=256 ----------
template<int EPI>
__global__ __launch_bounds__(256) void k_msgemm(const u16* __restrict__ Ah, const u16* __restrict__ Al,
    const u16* __restrict__ Bh, const u16* __restrict__ Bl,
    float* __restrict__ C, u16* __restrict__ Oh, u16* __restrict__ Ol){
  int tid=threadIdx.x, w=tid>>6, lane=tid&63, L=lane&15, q=lane>>4;
  int colBase=blockIdx.x<<6, rowBase=blockIdx.y<<6;
  const u16* ahp = Ah + (size_t)(rowBase + w*16 + L)*256 + q*8;
  const u16* alp = Al + (size_t)(rowBase + w*16 + L)*256 + q*8;
  const u16* bhp = Bh + (size_t)(colBase + L)*256 + q*8;
  const u16* blp = Bl + (size_t)(colBase + L)*256 + q*8;
  f4v z4={0.f,0.f,0.f,0.f};
  f4v acc[4]={z4,z4,z4,z4};
  for (int k0=0;k0<256;k0+=32){
    s8v ah=*(const s8v*)(ahp+k0), al=*(const s8v*)(alp+k0);
    #pragma unroll
    for (int t=0;t<4;t++){
      s8v bh=*(const s8v*)(bhp + (size_t)t*16*256 + k0);
      s8v bl=*(const s8v*)(blp + (size_t)t*16*256 + k0);
      acc[t]=MFMA(ah,bh,acc[t]);
      acc[t]=MFMA(ah,bl,acc[t]);
      acc[t]=MFMA(al,bh,acc[t]);
    }
  }
  #pragma unroll
  for (int t=0;t<4;t++){
    int col = colBase + t*16 + L;
    #pragma unroll
    for (int reg=0;reg<4;reg++){
      int row = rowBase + w*16 + q*4 + reg;
      size_t off = (size_t)row*256 + col;
      float v = acc[t][reg];
      if constexpr (EPI==0){ C[off] = v; }
      else { u16 h = f2b(v); Oh[off]=h; Ol[off]=f2b(v - b2f(h)); }
    }
  }
}

// ---------- split MFMA gram + bitpack ----------
__global__ __launch_bounds__(256) void k_mconnect(const u16* __restrict__ fah, const u16* __restrict__ fal,
    const u8* __restrict__ sel8, u32* __restrict__ conn){
  __shared__ u8 sg[64][64];
  int tid=threadIdx.x, w=tid>>6, lane=tid&63, L=lane&15, q=lane>>4;
  int b=blockIdx.z;
  int mBase=blockIdx.x*64, nBase=blockIdx.y*64;
  size_t bOff=(size_t)b*NN;
  const u16* ahp = fah + (bOff + nBase + w*16 + L)*256 + q*8;
  const u16* alp = fal + (bOff + nBase + w*16 + L)*256 + q*8;
  const u16* bhp = fah + (bOff + mBase + L)*256 + q*8;
  const u16* blp = fal + (bOff + mBase + L)*256 + q*8;
  f4v z4={0.f,0.f,0.f,0.f};
  f4v acc[4]={z4,z4,z4,z4};
  for (int k0=0;k0<256;k0+=32){
    s8v ah=*(const s8v*)(ahp+k0), al=*(const s8v*)(alp+k0);
    #pragma unroll
    for (int t=0;t<4;t++){
      s8v bh=*(const s8v*)(bhp + (size_t)t*16*256 + k0);
      s8v bl=*(const s8v*)(blp + (size_t)t*16*256 + k0);
      acc[t]=MFMA(ah,bh,acc[t]);
      acc[t]=MFMA(ah,bl,acc[t]);
      acc[t]=MFMA(al,bh,acc[t]);
    }
  }
  #pragma unroll
  for (int t=0;t<4;t++)
    #pragma unroll
    for (int reg=0;reg<4;reg++)
      sg[w*16 + q*4 + reg][t*16 + L] = acc[t][reg] > 0.f;
  __syncthreads();
  if (tid<128){
    int row=tid>>1, ww=tid&1;
    int nG = nBase+row;
    u32 word=0;
    if (sel8[b*NN + nG]){
      for (int j=0;j<32;j++){
        int m = mBase + ww*32 + j;
        if (sg[row][ww*32+j] && sel8[b*NN+m]) word |= (1u<<j);
      }
    }
    conn[((size_t)b*NN + nG)*32 + (mBase>>5) + ww] = word;
  }
}

// ---------- s1/s2 = V @ a1, V @ a2 ; grid (BN/4, heads) ----------
template<typename VT>
__global__ __launch_bounds__(256) void k_s1s2(const VT* __restrict__ V, int ldV, int colStep,
    const float* __restrict__ a1, const float* __restrict__ a2, int aStep,
    float* __restrict__ s1a, float* __restrict__ s2a){
  int h = blockIdx.y;
  int r = blockIdx.x*4 + (threadIdx.x>>6);
  int lane = threadIdx.x&63;
  float4 v;
  if constexpr (sizeof(VT)==2) v = ld4bf((const u16*)V + (size_t)r*ldV + h*colStep + lane*4);
  else                         v = *(const float4*)((const float*)V + (size_t)r*ldV + h*colStep + lane*4);
  const float* a1p = a1 + h*aStep; const float* a2p = a2 + h*aStep;
  float4 w1 = *(const float4*)(a1p+lane*4), w2 = *(const float4*)(a2p+lane*4);
  float d1 = v.x*w1.x+v.y*w1.y+v.z*w1.z+v.w*w1.w;
  float d2 = v.x*w2.x+v.y*w2.y+v.z*w2.z+v.w*w2.w;
  d1=wredsum(d1); d2=wredsum(d2);
  if (lane==0){ s1a[h*BN+r]=d1; s2a[h*BN+r]=d2; }
}

// ---------- row max of s2 over connected m (cheap; replaces rowstats) ----------
__global__ __launch_bounds__(256) void k_rowmax(const float* __restrict__ s2a,
    const u32* __restrict__ conn, float* __restrict__ M2a){
  int h = blockIdx.y;
  int r = blockIdx.x*4 + (threadIdx.x>>6);
  int lane = threadIdx.x&63;
  int b = r>>10;
  const float* s2p = s2a + h*BN + b*NN;
  float mx = -3.0e38f;
  #pragma unroll
  for (int t=0;t<16;t++){
    int m = lane + t*64;
    u32 wd = conn[(size_t)r*32 + (m>>5)];
    if ((wd>>(m&31))&1u) mx = fmaxf(mx, s2p[m]);
  }
  mx = wredmax(mx);
  if (lane==0) M2a[h*BN+r] = mx;
}

// ---------- MFMA GAT attention v2: Out = elu((P' @ V) / sum); grid (128, heads) ----------
// P built once per chunk (full 256-col output per block); online row-sum;
// row-max via rmx = leaky(s1 + M2) (leaky monotone => exact max of connected e).
template<typename VT>
__global__ __launch_bounds__(256) void k_mattn2(const float* __restrict__ s1a, const float* __restrict__ s2a,
    const float* __restrict__ M2a, const u32* __restrict__ conn,
    const VT* __restrict__ V, int vStride, int headMul, u16* __restrict__ Out, int oStride){
  __shared__ __align__(16) u16 Vt[256][40];   // Vt[d][m], 20 KB
  int tid=threadIdx.x, w=tid>>6, lane=tid&63, L=lane&15, q=lane>>4;
  int rowBase = blockIdx.x*64;
  int h = blockIdx.y;
  int hOff = h*headMul, sOff = h*BN;
  int b = rowBase>>10;
  size_t bOff = (size_t)b*NN;
  int r = rowBase + w*16 + L;
  float s1v = s1a[sOff+r];
  float rmv = leakyf(s1v + M2a[sOff+r]);
  const float* s2p = s2a + sOff + bOff;
  f4v z4={0.f,0.f,0.f,0.f};
  f4v acc[16];
  #pragma unroll
  for (int t=0;t<16;t++) acc[t]=z4;
  float sumP = 0.f;
  int sm_ = tid&31, sd0 = (tid>>5)*32;
  for (int k0=0;k0<NN;k0+=32){
    __syncthreads();
    {  // stage V[32 m][256 d] transposed -> Vt[d][m]
      const VT* vp = V + (bOff + k0 + sm_)*(size_t)vStride + hOff + sd0;
      #pragma unroll
      for (int g2=0; g2<4; g2++){
        u16 tmp[8];
        if constexpr (sizeof(VT)==2){
          *(uint4*)&tmp[0] = *(const uint4*)(vp + g2*8);
        } else {
          float vv[8]; load8((const float*)vp + g2*8, vv);
          #pragma unroll
          for (int i=0;i<8;i++) tmp[i]=f2b(vv[i]);
        }
        #pragma unroll
        for (int i=0;i<8;i++) Vt[sd0 + g2*8 + i][sm_] = tmp[i];
      }
    }
    u32 cw = conn[(size_t)r*32 + (k0>>5)];
    s8v pf;
    #pragma unroll
    for (int j=0;j<8;j++){
      int m = k0 + q*8 + j;
      float ev = ((cw>>(q*8+j))&1u) ? leakyf(s1v + s2p[m]) : -9.0e15f;
      float p = exp0(ev - rmv);
      sumP += p;
      pf[j] = (short)f2b(p);
    }
    __syncthreads();
    #pragma unroll
    for (int t=0;t<16;t++){
      s8v vf = *(const s8v*)&Vt[t*16 + L][q*8];
      acc[t] = MFMA(pf, vf, acc[t]);
    }
  }
  // row sums: lanes (L, q=0..3) share row L -> reduce over q
  sumP += __shfl_xor(sumP, 16);
  sumP += __shfl_xor(sumP, 32);
  // this lane outputs rows q*4+reg (wave-local); their sums live at lane q*4+reg
  float rsi[4];
  #pragma unroll
  for (int reg=0;reg<4;reg++) rsi[reg] = 1.f / __shfl(sumP, q*4+reg);
  #pragma unroll
  for (int t=0;t<16;t++){
    int col = hOff + t*16 + L;
    #pragma unroll
    for (int reg=0;reg<4;reg++){
      int row = rowBase + w*16 + q*4 + reg;
      Out[(size_t)row*oStride + col] = f2b(eluf(acc[t][reg]*rsi[reg]));
    }
  }
}

// ---------- LayerNorms ----------
__global__ __launch_bounds__(256) void k_ln_x(const float* __restrict__ x, const float* __restrict__ g,
                                              const float* __restrict__ bb, u16* __restrict__ out){
  int r = blockIdx.x*4 + (threadIdx.x>>6);
  int lane=threadIdx.x&63;
  float4 v = *(const float4*)(x + (size_t)r*DD + lane*4);
  float s = v.x+v.y+v.z+v.w;
  float s2 = v.x*v.x+v.y*v.y+v.z*v.z+v.w*v.w;
  s = wredsum(s); s2 = wredsum(s2);
  float mean = s*(1.f/256.f);
  float var = s2*(1.f/256.f) - mean*mean;
  float rstd = rsqrtf(var + 1e-5f);
  float4 gv = *(const float4*)(g+lane*4), bv = *(const float4*)(bb+lane*4);
  u16 t[4];
  t[0]=f2b((v.x-mean)*rstd*gv.x+bv.x); t[1]=f2b((v.y-mean)*rstd*gv.y+bv.y);
  t[2]=f2b((v.z-mean)*rstd*gv.z+bv.z); t[3]=f2b((v.w-mean)*rstd*gv.w+bv.w);
  *(uint2*)(out + (size_t)r*DD + lane*4) = *(uint2*)&t[0];
}

__global__ __launch_bounds__(256) void k_ln_kv(const u16* __restrict__ gout, const float* __restrict__ pe,
    const u8* __restrict__ sel8, const float* __restrict__ g, const float* __restrict__ bb,
    u16* __restrict__ out){
  int r = blockIdx.x*4 + (threadIdx.x>>6);
  int lane=threadIdx.x&63;
  int n = r & 1023;
  float4 v = make_float4(0.f,0.f,0.f,0.f);
  if (sel8[r]){
    float4 gv = ld4bf(gout + (size_t)r*DD + lane*4);
    float4 pv = *(const float4*)(pe + (size_t)n*DD + lane*4);
    v = make_float4(gv.x+pv.x, gv.y+pv.y, gv.z+pv.z, gv.w+pv.w);
  }
  float s = v.x+v.y+v.z+v.w;
  float s2 = v.x*v.x+v.y*v.y+v.z*v.z+v.w*v.w;
  s = wredsum(s); s2 = wredsum(s2);
  float mean = s*(1.f/256.f);
  float var = s2*(1.f/256.f) - mean*mean;
  float rstd = rsqrtf(var + 1e-5f);
  float4 gv = *(const float4*)(g+lane*4), bv = *(const float4*)(bb+lane*4);
  u16 t[4];
  t[0]=f2b((v.x-mean)*rstd*gv.x+bv.x); t[1]=f2b((v.y-mean)*rstd*gv.y+bv.y);
  t[2]=f2b((v.z-mean)*rstd*gv.z+bv.z); t[3]=f2b((v.w-mean)*rstd*gv.w+bv.w);
  *(uint2*)(out + (size_t)r*DD + lane*4) = *(uint2*)&t[0];
}

// ---------- MFMA CA stats ----------
__global__ __launch_bounds__(256) void k_mca_stats(const u16* __restrict__ q, const u16* __restrict__ k,
    const u8* __restrict__ sel8, float* __restrict__ cmax, float* __restrict__ cinv){
  __shared__ __align__(16) u16 Qls[64][72];
  __shared__ __align__(16) u16 Kls[64][72];
  __shared__ float cw4[4];
  int tid=threadIdx.x;
  int w = tid>>6, lane = tid&63, L = lane&15, qd = lane>>4;
  int b=blockIdx.z, h=blockIdx.y, rowBase=blockIdx.x*64;
  size_t bOff = (size_t)b*NN;
  {
    float c = 0.f;
    #pragma unroll
    for (int i=0;i<4;i++) c += sel8[b*NN + tid*4 + i] ? 0.f : 1.f;
    c = wredsum(c);
    if (lane==0) cw4[w]=c;
  }
  {
    int r=tid>>2, c0=(tid&3)*16;
    size_t base = (bOff + rowBase + r)*(size_t)DD + h*64 + c0;
    *(uint4*)&Qls[r][c0]   = *(const uint4*)(q + base);
    *(uint4*)&Qls[r][c0+8] = *(const uint4*)(q + base + 8);
  }
  float um[4], us[4];
  #pragma unroll
  for (int i=0;i<4;i++){ um[i]=-3.0e38f; us[i]=0.f; }
  for (int m0=0;m0<NN;m0+=64){
    __syncthreads();
    {
      int r=tid>>2, c0=(tid&3)*16;
      size_t base = (bOff + m0 + r)*(size_t)DD + h*64 + c0;
      *(uint4*)&Kls[r][c0]   = *(const uint4*)(k + base);
      *(uint4*)&Kls[r][c0+8] = *(const uint4*)(k + base + 8);
    }
    __syncthreads();
    f4v zero = {0.f,0.f,0.f,0.f};
    f4v sa[4] = {zero,zero,zero,zero};
    #pragma unroll
    for (int kc=0;kc<64;kc+=32){
      s8v af = *(const s8v*)&Qls[w*16 + L][kc + qd*8];
      #pragma unroll
      for (int t=0;t<4;t++){
        s8v bfr = *(const s8v*)&Kls[t*16 + L][kc + qd*8];
        sa[t] = MFMA(af, bfr, sa[t]);
      }
    }
    #pragma unroll
    for (int t=0;t<4;t++){
      int m = m0 + t*16 + L;
      if (sel8[b*NN+m]){
        #pragma unroll
        for (int reg=0;reg<4;reg++){
          float val = sa[t][reg]*0.125f;
          float nm = fmaxf(um[reg], val);
          us[reg] = us[reg]*exp0(um[reg]-nm) + exp0(val-nm);
          um[reg] = nm;
        }
      }
    }
  }
  #pragma unroll
  for (int off=1;off<16;off<<=1){
    #pragma unroll
    for (int reg=0;reg<4;reg++){
      float om = __shfl_xor(um[reg], off);
      float os = __shfl_xor(us[reg], off);
      float nm = fmaxf(um[reg], om);
      us[reg] = us[reg]*exp0(um[reg]-nm) + os*exp0(om-nm);
      um[reg] = nm;
    }
  }
  __syncthreads();
  float cn = cw4[0]+cw4[1]+cw4[2]+cw4[3];
  if (L==0){
    #pragma unroll
    for (int reg=0;reg<4;reg++){
      int row = rowBase + w*16 + qd*4 + reg;
      float M = um[reg];
      if (cn>0.f) M = fmaxf(M, -1.0e9f);
      float S = cn*exp0(-1.0e9f - M) + us[reg]*exp0(um[reg]-M);
      size_t o = ((size_t)b*HC+h)*NN + row;
      cmax[o]=M; cinv[o]=1.f/S;
    }
  }
}

// ---------- MFMA CA attention ----------
__global__ __launch_bounds__(256) void k_mca_av(const u16* __restrict__ q, const u16* __restrict__ k,
    const u16* __restrict__ v, const u8* __restrict__ sel8,
    const float* __restrict__ cmax, const float* __restrict__ cinv, u16* __restrict__ O){
  __shared__ __align__(16) u16 Qls[64][72];
  __shared__ __align__(16) u16 KP[64][72];
  __shared__ __align__(16) u16 Vt[64][72];
  int tid=threadIdx.x;
  int w = tid>>6, lane = tid&63, L = lane&15, qd = lane>>4;
  int b=blockIdx.z, h=blockIdx.y, rowBase=blockIdx.x*64;
  size_t bOff = (size_t)b*NN;
  {
    int r=tid>>2, c0=(tid&3)*16;
    size_t base = (bOff + rowBase + r)*(size_t)DD + h*64 + c0;
    *(uint4*)&Qls[r][c0]   = *(const uint4*)(q + base);
    *(uint4*)&Qls[r][c0+8] = *(const uint4*)(q + base + 8);
  }
  float rm[4], ri[4];
  #pragma unroll
  for (int reg=0;reg<4;reg++){
    size_t o = ((size_t)b*HC+h)*NN + rowBase + w*16 + qd*4 + reg;
    rm[reg]=cmax[o]; ri[reg]=cinv[o];
  }
  f4v zero = {0.f,0.f,0.f,0.f};
  f4v acc[4] = {zero,zero,zero,zero};
  int svm = tid&63, svd0 = (tid>>6)*16;
  for (int m0=0;m0<NN;m0+=64){
    __syncthreads();
    {
      int r=tid>>2, c0=(tid&3)*16;
      size_t base = (bOff + m0 + r)*(size_t)DD + h*64 + c0;
      *(uint4*)&KP[r][c0]   = *(const uint4*)(k + base);
      *(uint4*)&KP[r][c0+8] = *(const uint4*)(k + base + 8);
      size_t vb_ = (bOff + m0 + svm)*(size_t)DD + h*64 + svd0;
      uint4 u0 = *(const uint4*)(v + vb_);
      uint4 u1 = *(const uint4*)(v + vb_ + 8);
      u16 tmp[16];
      *(uint4*)&tmp[0]=u0; *(uint4*)&tmp[8]=u1;
      #pragma unroll
      for (int i=0;i<16;i++) Vt[svd0+i][svm] = tmp[i];
    }
    __syncthreads();
    f4v sa[4] = {zero,zero,zero,zero};
    #pragma unroll
    for (int kc=0;kc<64;kc+=32){
      s8v af = *(const s8v*)&Qls[w*16 + L][kc + qd*8];
      #pragma unroll
      for (int t=0;t<4;t++){
        s8v bfr = *(const s8v*)&KP[t*16 + L][kc + qd*8];
        sa[t] = MFMA(af, bfr, sa[t]);
      }
    }
    __syncthreads();
    #pragma unroll
    for (int t=0;t<4;t++){
      int m = m0 + t*16 + L;
      bool sl = sel8[b*NN+m];
      #pragma unroll
      for (int reg=0;reg<4;reg++){
        float val = sl ? sa[t][reg]*0.125f : -1.0e9f;
        KP[w*16 + qd*4 + reg][t*16 + L] = f2b(exp0(val - rm[reg])*ri[reg]);
      }
    }
    __syncthreads();
    #pragma unroll
    for (int mc=0;mc<64;mc+=32){
      s8v pf = *(const s8v*)&KP[w*16 + L][mc + qd*8];
      #pragma unroll
      for (int t=0;t<4;t++){
        s8v vf = *(const s8v*)&Vt[t*16 + L][mc + qd*8];
        acc[t] = MFMA(pf, vf, acc[t]);
      }
    }
  }
  #pragma unroll
  for (int t=0;t<4;t++){
    int col = h*64 + t*16 + L;
    #pragma unroll
    for (int reg=0;reg<4;reg++){
      int row = rowBase + w*16 + qd*4 + reg;
      O[(bOff + row)*(size_t)DD + col] = f2b(acc[t][reg]);
    }
  }
}

extern "C" void kernel_launch(void* const* d_in, const int* in_sizes, int n_in,
                              void* d_out, int out_size, void* d_ws, size_t ws_size,
                              hipStream_t stream) {
  (void)in_sizes; (void)n_in; (void)out_size;
  const float* x      = (const float*)d_in[0];
  const int*   mask   = (const int*  )d_in[1];
  const float* pe     = (const float*)d_in[2];
  const float* sim_Wx = (const float*)d_in[3];
  const float* sim_Wq = (const float*)d_in[4];
  const float* adj_W  = (const float*)d_in[5];
  const float* gat_W  = (const float*)d_in[6];
  const float* gat_a1 = (const float*)d_in[7];
  const float* gat_a2 = (const float*)d_in[8];
  const float* gat_Wo = (const float*)d_in[9];
  const float* gat_ao1= (const float*)d_in[10];
  const float* gat_ao2= (const float*)d_in[11];
  const float* ln3_g  = (const float*)d_in[12];
  const float* ln3_b  = (const float*)d_in[13];
  const float* ln4_g  = (const float*)d_in[14];
  const float* ln4_b  = (const float*)d_in[15];
  const float* ca_Wq  = (const float*)d_in[16];
  const float* ca_Wk  = (const float*)d_in[17];
  const float* ca_Wv  = (const float*)d_in[18];
  const float* ca_Wp  = (const float*)d_in[19];
  const float* gamma  = (const float*)d_in[20];
  float* out    = (float*)d_out;
  float* simOut = out + (size_t)BN*DD;

  const size_t MB = 1024*1024;
  bool big = ws_size >= 98*MB;
  char* W = (char*)d_ws;
  float* pq   = (float*)W;
  float* cnt  = pq + 2048;
  float* sq   = cnt + 16;
  float* s1a  = (float*)(W + 64*1024);
  float* s2a  = (float*)(W + 320*1024);
  float* M2a  = (float*)(W + 576*1024);
  float* cam  = (float*)(W + 1088*1024);
  float* civ  = (float*)(W + 1216*1024);
  u8*    sel8 = (u8*)(W + 1400*1024);
  u32*   conn = (u32*)(W + 2*MB);
  u16*   WT0  = (u16*)(W + 3*MB);
  u16*   WoT  = (u16*)(W + 4*MB);
  u16*   WQT  = (u16*)(W + 5*MB);
  u16*   WKT  = WQT + 65536;
  u16*   WVT  = WKT + 65536;
  u16*   WPT  = WVT + 65536;
  u16*   sWxh = (u16*)(W + 5*MB + 512*1024);
  u16*   sWxl = sWxh + 65536;
  u16*   aWh  = sWxl + 65536;
  u16*   aWl  = aWh + 65536;
  u16*   xh   = (u16*)(W + 6*MB);
  u16*   xl   = (u16*)(W + 10*MB);
  float* S0   = (float*)(W + 14*MB);
  u16*   fah  = (u16*)(W + 22*MB);
  u16*   fal  = (u16*)(W + 26*MB);
  u16*   T2   = (u16*)(W + 30*MB);

  // prep
  k_split<<<BN*DD/2048,256,0,stream>>>(x, xh, xl);
  k_transpose<<<dim3(4,4,HG),256,0,stream>>>(gat_W, WT0, 256, 65536);
  k_transpose<<<dim3(4,32,1),256,0,stream>>>(gat_Wo, WoT, 2048, 0);
  k_transpose<<<dim3(4,4,1),256,0,stream>>>(ca_Wq, WQT, 256, 0);
  k_transpose<<<dim3(4,4,1),256,0,stream>>>(ca_Wk, WKT, 256, 0);
  k_transpose<<<dim3(4,4,1),256,0,stream>>>(ca_Wv, WVT, 256, 0);
  k_transpose<<<dim3(4,4,1),256,0,stream>>>(ca_Wp, WPT, 256, 0);
  k_transp_split<<<dim3(4,4,1),256,0,stream>>>(sim_Wx, sWxh, sWxl);
  k_transp_split<<<dim3(4,4,1),256,0,stream>>>(adj_W, aWh, aWl);

  hipMemsetAsync(pq, 0, (2048+16)*sizeof(float), stream);
  k_posq<<<dim3(BB,16),256,0,stream>>>(x, mask, pq, cnt);
  k_sq<<<BB,256,0,stream>>>(pq, cnt, sim_Wq, sq);
  k_msgemm<0><<<dim3(4,128),256,0,stream>>>(xh, xl, sWxh, sWxl, S0, nullptr, nullptr);  // y
  k_simsel<<<BN/4,256,0,stream>>>(S0, sq, simOut, sel8);
  k_msgemm<4><<<dim3(4,128),256,0,stream>>>(xh, xl, aWh, aWl, nullptr, fah, fal);       // fa split
  k_mconnect<<<dim3(16,16,BB),256,0,stream>>>(fah, fal, sel8, conn);

  if (big){
    u16* whcat = (u16*)(W + 34*MB);
    u16* htcat = (u16*)(W + 66*MB);
    u16* qx = (u16*)(W + 34*MB);
    u16* kv = (u16*)(W + 38*MB);
    u16* qb = (u16*)(W + 42*MB);
    u16* kb = (u16*)(W + 46*MB);
    u16* vb = (u16*)(W + 50*MB);
    u16* Ob = (u16*)(W + 54*MB);

    k_mgemm<3><<<dim3(32,128),256,0,stream>>>(xh, WT0, 256, 256, nullptr, nullptr, nullptr, whcat); // Wh_cat
    k_s1s2<u16><<<dim3(BN/4,HG),256,0,stream>>>(whcat, 2048, 256, gat_a1, gat_a2, 256, s1a, s2a);
    k_rowmax<<<dim3(BN/4,HG),256,0,stream>>>(s2a, conn, M2a);
    k_mattn2<u16><<<dim3(128,HG),256,0,stream>>>(s1a, s2a, M2a, conn, whcat, 2048, 256, htcat, 2048);
    k_mgemm<0><<<dim3(4,128),256,0,stream>>>(htcat, WoT, 2048, 2048, S0, nullptr, nullptr, nullptr); // Who fp32
    k_s1s2<float><<<dim3(BN/4,1),256,0,stream>>>(S0, 256, 0, gat_ao1, gat_ao2, 0, s1a, s2a);
    k_rowmax<<<dim3(BN/4,1),256,0,stream>>>(s2a, conn, M2a);
    k_mattn2<float><<<dim3(128,1),256,0,stream>>>(s1a, s2a, M2a, conn, S0, 256, 0, T2, 256);  // gout

    k_ln_x<<<BN/4,256,0,stream>>>(x, ln3_g, ln3_b, qx);
    k_ln_kv<<<BN/4,256,0,stream>>>(T2, pe, sel8, ln4_g, ln4_b, kv);
    k_mgemm<3><<<dim3(4,128),256,0,stream>>>(qx, WQT, 256, 256, nullptr, nullptr, nullptr, qb);
    k_mgemm<3><<<dim3(4,128),256,0,stream>>>(kv, WKT, 256, 256, nullptr, nullptr, nullptr, kb);
    k_mgemm<3><<<dim3(4,128),256,0,stream>>>(kv, WVT, 256, 256, nullptr, nullptr, nullptr, vb);
    k_mca_stats<<<dim3(16,HC,BB),256,0,stream>>>(qb, kb, sel8, cam, civ);
    k_mca_av<<<dim3(16,HC,BB),256,0,stream>>>(qb, kb, vb, sel8, cam, civ, Ob);
    k_mgemm<2><<<dim3(4,128),256,0,stream>>>(Ob, WPT, 256, 256, out, x, gamma, nullptr);
  } else {
    u16* T0 = fah;
    u16* T1 = fal;
    u16* S0b = (u16*)S0;
    hipMemsetAsync(S0, 0, 8*MB, stream);
    for (int h=0;h<HG;h++){
      k_mgemm<3><<<dim3(4,128),256,0,stream>>>(xh, WT0 + (size_t)h*65536, 256, 256, nullptr, nullptr, nullptr, T0);
      k_s1s2<u16><<<dim3(BN/4,1),256,0,stream>>>(T0, 256, 0, gat_a1 + h*DD, gat_a2 + h*DD, 0, s1a, s2a);
      k_rowmax<<<dim3(BN/4,1),256,0,stream>>>(s2a, conn, M2a);
      k_mattn2<u16><<<dim3(128,1),256,0,stream>>>(s1a, s2a, M2a, conn, T0, 256, 0, T1, 256);
      k_mgemm<1><<<dim3(4,128),256,0,stream>>>(T1, WoT + (size_t)h*256, 256, 2048, S0, nullptr, nullptr, nullptr);
    }
    k_s1s2<float><<<dim3(BN/4,1),256,0,stream>>>(S0, 256, 0, gat_ao1, gat_ao2, 0, s1a, s2a);
    k_rowmax<<<dim3(BN/4,1),256,0,stream>>>(s2a, conn, M2a);
    k_mattn2<float><<<dim3(128,1),256,0,stream>>>(s1a, s2a, M2a, conn, S0, 256, 0, T2, 256); // gout

    k_ln_x<<<BN/4,256,0,stream>>>(x, ln3_g, ln3_b, T1);
    k_ln_kv<<<BN/4,256,0,stream>>>(T2, pe, sel8, ln4_g, ln4_b, T0);
    k_mgemm<3><<<dim3(4,128),256,0,stream>>>(T1, WQT, 256, 256, nullptr, nullptr, nullptr, T2);
    k_mgemm<3><<<dim3(4,128),256,0,stream>>>(T0, WKT, 256, 256, nullptr, nullptr, nullptr, T1);
    k_mgemm<3><<<dim3(4,128),256,0,stream>>>(T0, WVT, 256, 256, nullptr, nullptr, nullptr, S0b);
    k_mca_stats<<<dim3(16,HC,BB),256,0,stream>>>(T2, T1, sel8, cam, civ);
    k_mca_av<<<dim3(16,HC,BB),256,0,stream>>>(T2, T1, S0b, sel8, cam, civ, T0);
    k_mgemm<2><<<dim3(4,128),256,0,stream>>>(T0, WPT, 256, 256, out, x, gamma, nullptr);
  }
}

// Round 9
// 890.428 us; speedup vs baseline: 1.9883x; 1.0433x over previous
//
#include <hip/hip_runtime.h>
#include <hip/hip_bf16.h>

// GATFusionBlockPosOnly: B=8, N=1024, D=256, 8 GAT heads, 4 CA heads.
// Round 9:
//  - k_mattn2: software-pipelined (double-buffered LDS V, prefetch issued before
//    P-build, ONE barrier/iter), col-tiling template NT (single-head runs use
//    NT=8 -> 2x blocks).
//  - CA: k_mca_stats -> k_mca_max (exp-free max pass); k_mca_av normalizes in
//    epilogue with online row-sum (GAT-style).
//  - Fused: 4 CA transposes -> k_transpose4; q/k/v projections -> k_mgemm3.

#define BB 8
#define NN 1024
#define DD 256
#define HG 8
#define HC 4
#define BN (BB*NN)

typedef unsigned short u16;
typedef unsigned int u32;
typedef unsigned char u8;
typedef __attribute__((ext_vector_type(8))) short s8v;   // 8 bf16
typedef __attribute__((ext_vector_type(4))) float f4v;   // 4 fp32 acc
#define MFMA(a,b,c) __builtin_amdgcn_mfma_f32_16x16x32_bf16((a),(b),(c),0,0,0)

__device__ __forceinline__ u16 f2b(float x){
  union{ float f; unsigned u; } a; a.f = x;
  unsigned r = a.u + 0x7fff + ((a.u>>16)&1);
  return (u16)(r>>16);
}
__device__ __forceinline__ float b2f(u16 b){ return __uint_as_float(((unsigned)b)<<16); }
__device__ __forceinline__ float4 ld4bf(const u16* p){
  uint2 u = *(const uint2*)p;
  float4 r;
  r.x=__uint_as_float(u.x<<16); r.y=__uint_as_float(u.x&0xffff0000u);
  r.z=__uint_as_float(u.y<<16); r.w=__uint_as_float(u.y&0xffff0000u);
  return r;
}
__device__ __forceinline__ void load8(const float* p, float* v){
  float4 a=*(const float4*)p, b=*(const float4*)(p+4);
  v[0]=a.x;v[1]=a.y;v[2]=a.z;v[3]=a.w;v[4]=b.x;v[5]=b.y;v[6]=b.z;v[7]=b.w;
}
__device__ __forceinline__ float wredsum(float v){
  #pragma unroll
  for(int o=32;o>0;o>>=1) v += __shfl_xor(v,o);
  return v;
}
__device__ __forceinline__ float wredmax(float v){
  #pragma unroll
  for(int o=32;o>0;o>>=1) v = fmaxf(v,__shfl_xor(v,o));
  return v;
}
__device__ __forceinline__ float eluf(float x){ return x>0.f ? x : expm1f(x); }
__device__ __forceinline__ float leakyf(float z){ return z>=0.f ? z : 0.2f*z; }
__device__ __forceinline__ float exp0(float a){ return expf(fminf(a, 0.f)); }
__device__ __forceinline__ float flushf(float v){ return (fabsf(v) < 1.0e30f) ? v : 0.f; }

// ---------- fp32 -> (hi,lo) bf16 split ----------
__global__ __launch_bounds__(256) void k_split(const float* __restrict__ X, u16* __restrict__ H, u16* __restrict__ Lo){
  size_t i = ((size_t)blockIdx.x*256 + threadIdx.x)*8;
  float v[8]; load8(X+i, v);
  u16 hh[8], ll[8];
  #pragma unroll
  for (int j=0;j<8;j++){ hh[j]=f2b(v[j]); ll[j]=f2b(v[j]-b2f(hh[j])); }
  *(uint4*)(H+i)=*(uint4*)&hh[0];
  *(uint4*)(Lo+i)=*(uint4*)&ll[0];
}

// ---------- transpose fp32 [R][C] -> bf16 [C][R]; grid (C/64, R/64, slices) ----------
__global__ __launch_bounds__(256) void k_transpose(const float* __restrict__ S, u16* __restrict__ D,
                                                   int R, int sliceElems){
  __shared__ float tl[64][65];
  const float* src = S + (size_t)blockIdx.z*sliceElems;
  u16* dst = D + (size_t)blockIdx.z*sliceElems;
  int C = gridDim.x*64;
  int bx=blockIdx.x*64, by=blockIdx.y*64;
  int tid=threadIdx.x, r=tid>>2, c0=(tid&3)*16;
  #pragma unroll
  for (int i=0;i<16;i+=4){
    float4 v = *(const float4*)(src + (size_t)(by+r)*C + bx + c0 + i);
    tl[r][c0+i]=v.x; tl[r][c0+i+1]=v.y; tl[r][c0+i+2]=v.z; tl[r][c0+i+3]=v.w;
  }
  __syncthreads();
  u16 tmp[16];
  #pragma unroll
  for (int i=0;i<16;i++) tmp[i] = f2b(tl[c0+i][r]);
  *(uint4*)(dst + (size_t)(bx+r)*R + by + c0)     = *(uint4*)&tmp[0];
  *(uint4*)(dst + (size_t)(bx+r)*R + by + c0 + 8) = *(uint4*)&tmp[8];
}

// ---------- 4x 256x256 transposes in one launch (grid (4,4,4)) ----------
__global__ __launch_bounds__(256) void k_transpose4(const float* __restrict__ Sa, const float* __restrict__ Sb,
    const float* __restrict__ Sc, const float* __restrict__ Sd, u16* __restrict__ D){
  __shared__ float tl[64][65];
  const float* src = blockIdx.z==0 ? Sa : blockIdx.z==1 ? Sb : blockIdx.z==2 ? Sc : Sd;
  u16* dst = D + (size_t)blockIdx.z*65536;
  int bx=blockIdx.x*64, by=blockIdx.y*64;
  int tid=threadIdx.x, r=tid>>2, c0=(tid&3)*16;
  #pragma unroll
  for (int i=0;i<16;i+=4){
    float4 v = *(const float4*)(src + (size_t)(by+r)*256 + bx + c0 + i);
    tl[r][c0+i]=v.x; tl[r][c0+i+1]=v.y; tl[r][c0+i+2]=v.z; tl[r][c0+i+3]=v.w;
  }
  __syncthreads();
  u16 tmp[16];
  #pragma unroll
  for (int i=0;i<16;i++) tmp[i] = f2b(tl[c0+i][r]);
  *(uint4*)(dst + (size_t)(bx+r)*256 + by + c0)     = *(uint4*)&tmp[0];
  *(uint4*)(dst + (size_t)(bx+r)*256 + by + c0 + 8) = *(uint4*)&tmp[8];
}

// ---------- transpose + split: fp32 [256][256] -> hi/lo bf16 [256][256] ----------
__global__ __launch_bounds__(256) void k_transp_split(const float* __restrict__ S, u16* __restrict__ DH, u16* __restrict__ DL){
  __shared__ float tl[64][65];
  int bx=blockIdx.x*64, by=blockIdx.y*64;
  int tid=threadIdx.x, r=tid>>2, c0=(tid&3)*16;
  #pragma unroll
  for (int i=0;i<16;i+=4){
    float4 v = *(const float4*)(S + (size_t)(by+r)*256 + bx + c0 + i);
    tl[r][c0+i]=v.x; tl[r][c0+i+1]=v.y; tl[r][c0+i+2]=v.z; tl[r][c0+i+3]=v.w;
  }
  __syncthreads();
  u16 th[16], tll[16];
  #pragma unroll
  for (int i=0;i<16;i++){
    float v = tl[c0+i][r];
    th[i]=f2b(v); tll[i]=f2b(v - b2f(th[i]));
  }
  *(uint4*)(DH + (size_t)(bx+r)*256 + by + c0)     = *(uint4*)&th[0];
  *(uint4*)(DH + (size_t)(bx+r)*256 + by + c0 + 8) = *(uint4*)&th[8];
  *(uint4*)(DL + (size_t)(bx+r)*256 + by + c0)     = *(uint4*)&tll[0];
  *(uint4*)(DL + (size_t)(bx+r)*256 + by + c0 + 8) = *(uint4*)&tll[8];
}

// ---------- pos_query ----------
__global__ __launch_bounds__(256) void k_posq(const float* __restrict__ x, const int* __restrict__ mask,
                                              float* __restrict__ pq, float* __restrict__ cnt){
  int b = blockIdx.x, chunk = blockIdx.y;
  int d = threadIdx.x;
  int n0 = chunk*64;
  float acc = 0.f; float c = 0.f;
  for (int i=0;i<64;i++){
    int n = n0+i;
    if (mask[b*NN+n]==1){ acc += x[((size_t)(b*NN+n))*DD + d]; c += 1.f; }
  }
  atomicAdd(&pq[b*DD+d], acc);
  if (d==0) atomicAdd(&cnt[b], c);
}

__global__ __launch_bounds__(256) void k_sq(const float* __restrict__ pq, const float* __restrict__ cnt,
                                            const float* __restrict__ Wq, float* __restrict__ sq){
  int b = blockIdx.x, e = threadIdx.x;
  float inv = 1.f / fmaxf(cnt[b], 1.f);
  float acc=0.f;
  for (int d0=0; d0<DD; d0++) acc += (pq[b*DD+d0]*inv) * Wq[d0*DD+e];
  sq[b*DD+e] = acc;
}

__global__ __launch_bounds__(256) void k_simsel(const float* __restrict__ y, const float* __restrict__ sq,
                                                float* __restrict__ simOut, u8* __restrict__ sel8){
  int r = blockIdx.x*4 + (threadIdx.x>>6);
  int lane = threadIdx.x & 63;
  int b = r>>10;
  float4 yv = *(const float4*)(y + (size_t)r*DD + lane*4);
  float4 qv = *(const float4*)(sq + b*DD + lane*4);
  float p = yv.x*qv.x + yv.y*qv.y + yv.z*qv.z + yv.w*qv.w;
  p = wredsum(p);
  if (lane==0){
    float s = p * 0.0625f;
    float sim = 1.f/(1.f+expf(-s));
    simOut[r] = sim;
    sel8[r] = (sim > 0.97f) ? 1 : 0;
  }
}

// ---------- no-LDS MFMA GEMM: out[8192, OC] = A[8192,KK] @ BT[OC,KK]^T ----------
template<int EPI>
__global__ __launch_bounds__(256) void k_mgemm(const u16* __restrict__ A, const u16* __restrict__ BT,
    int KK, int ldB, float* __restrict__ C, const float* __restrict__ Xres,
    const float* __restrict__ gamma, u16* __restrict__ O){
  int tid=threadIdx.x, w=tid>>6, lane=tid&63, L=lane&15, q=lane>>4;
  int OC = gridDim.x<<6;
  int colBase=blockIdx.x<<6, rowBase=blockIdx.y<<6;
  const u16* ap = A + (size_t)(rowBase + w*16 + L)*KK + q*8;
  const u16* bp = BT + (size_t)(colBase + L)*ldB + q*8;
  size_t bs = (size_t)16*ldB;
  f4v z4={0.f,0.f,0.f,0.f};
  f4v acc[4]={z4,z4,z4,z4};
  s8v a0 = *(const s8v*)ap;
  s8v b0 = *(const s8v*)bp;
  s8v b1 = *(const s8v*)(bp + bs);
  s8v b2 = *(const s8v*)(bp + 2*bs);
  s8v b3 = *(const s8v*)(bp + 3*bs);
  for (int k0=32;k0<KK;k0+=32){
    s8v an  = *(const s8v*)(ap + k0);
    s8v bn0 = *(const s8v*)(bp + k0);
    s8v bn1 = *(const s8v*)(bp + bs + k0);
    s8v bn2 = *(const s8v*)(bp + 2*bs + k0);
    s8v bn3 = *(const s8v*)(bp + 3*bs + k0);
    acc[0]=MFMA(a0,b0,acc[0]); acc[1]=MFMA(a0,b1,acc[1]);
    acc[2]=MFMA(a0,b2,acc[2]); acc[3]=MFMA(a0,b3,acc[3]);
    a0=an; b0=bn0; b1=bn1; b2=bn2; b3=bn3;
  }
  acc[0]=MFMA(a0,b0,acc[0]); acc[1]=MFMA(a0,b1,acc[1]);
  acc[2]=MFMA(a0,b2,acc[2]); acc[3]=MFMA(a0,b3,acc[3]);
  #pragma unroll
  for (int t=0;t<4;t++){
    int col = colBase + t*16 + L;
    #pragma unroll
    for (int reg=0;reg<4;reg++){
      int row = rowBase + w*16 + q*4 + reg;
      size_t off = (size_t)row*OC + col;
      float v = acc[t][reg];
      if constexpr (EPI==0){ C[off] = v; }
      else if constexpr (EPI==1){ C[off] += v; }
      else if constexpr (EPI==2){ C[off] = flushf(Xres[off] + gamma[col]*v); }
      else { O[off] = f2b(v); }
    }
  }
}

// ---------- fused q/k/v projections: grid (4,128,3); weights contiguous; out stride 2M u16 ----------
__global__ __launch_bounds__(256) void k_mgemm3(const u16* __restrict__ Aq, const u16* __restrict__ Akv,
    const u16* __restrict__ BT0, u16* __restrict__ O0){
  int tid=threadIdx.x, w=tid>>6, lane=tid&63, L=lane&15, q=lane>>4;
  const u16* A = blockIdx.z==0 ? Aq : Akv;
  const u16* BT = BT0 + (size_t)blockIdx.z*65536;
  u16* O = O0 + (size_t)blockIdx.z*2097152;
  int colBase=blockIdx.x<<6, rowBase=blockIdx.y<<6;
  const u16* ap = A + (size_t)(rowBase + w*16 + L)*256 + q*8;
  const u16* bp = BT + (size_t)(colBase + L)*256 + q*8;
  size_t bs = (size_t)16*256;
  f4v z4={0.f,0.f,0.f,0.f};
  f4v acc[4]={z4,z4,z4,z4};
  #pragma unroll
  for (int k0=0;k0<256;k0+=32){
    s8v a0 = *(const s8v*)(ap + k0);
    #pragma unroll
    for (int t=0;t<4;t++){
      s8v bt = *(const s8v*)(bp + (size_t)t*bs + k0);
      acc[t]=MFMA(a0,bt,acc[t]);
    }
  }
  #pragma unroll
  for (int t=0;t<4;t++){
    int col = colBase + t*16 + L;
    #pragma unroll
    for (int reg=0;reg<4;reg++){
      int row = rowBase + w*16 + q*4 + reg;
      O[(size_t)row*256 + col] = f2b(acc[t][reg]);
    }
  }
}

// ---------- split (3-term) MFMA GEMM: KK=256, OC=256 ----------
template<int EPI>
__global__ __launch_bounds__(256) void k_msgemm(const u16* __restrict__ Ah, const u16* __restrict__ Al,
    const u16* __restrict__ Bh, const u16* __restrict__ Bl,
    float* __restrict__ C, u16* __restrict__ Oh, u16* __restrict__ Ol){
  int tid=threadIdx.x, w=tid>>6, lane=tid&63, L=lane&15, q=lane>>4;
  int colBase=blockIdx.x<<6, rowBase=blockIdx.y<<6;
  const u16* ahp = Ah + (size_t)(rowBase + w*16 + L)*256 + q*8;
  const u16* alp = Al + (size_t)(rowBase + w*16 + L)*256 + q*8;
  const u16* bhp = Bh + (size_t)(colBase + L)*256 + q*8;
  const u16* blp = Bl + (size_t)(colBase + L)*256 + q*8;
  f4v z4={0.f,0.f,0.f,0.f};
  f4v acc[4]={z4,z4,z4,z4};
  for (int k0=0;k0<256;k0+=32){
    s8v ah=*(const s8v*)(ahp+k0), al=*(const s8v*)(alp+k0);
    #pragma unroll
    for (int t=0;t<4;t++){
      s8v bh=*(const s8v*)(bhp + (size_t)t*16*256 + k0);
      s8v bl=*(const s8v*)(blp + (size_t)t*16*256 + k0);
      acc[t]=MFMA(ah,bh,acc[t]);
      acc[t]=MFMA(ah,bl,acc[t]);
      acc[t]=MFMA(al,bh,acc[t]);
    }
  }
  #pragma unroll
  for (int t=0;t<4;t++){
    int col = colBase + t*16 + L;
    #pragma unroll
    for (int reg=0;reg<4;reg++){
      int row = rowBase + w*16 + q*4 + reg;
      size_t off = (size_t)row*256 + col;
      float v = acc[t][reg];
      if constexpr (EPI==0){ C[off] = v; }
      else { u16 h = f2b(v); Oh[off]=h; Ol[off]=f2b(v - b2f(h)); }
    }
  }
}

// ---------- split MFMA gram + bitpack ----------
__global__ __launch_bounds__(256) void k_mconnect(const u16* __restrict__ fah, const u16* __restrict__ fal,
    const u8* __restrict__ sel8, u32* __restrict__ conn){
  __shared__ u8 sg[64][64];
  int tid=threadIdx.x, w=tid>>6, lane=tid&63, L=lane&15, q=lane>>4;
  int b=blockIdx.z;
  int mBase=blockIdx.x*64, nBase=blockIdx.y*64;
  size_t bOff=(size_t)b*NN;
  const u16* ahp = fah + (bOff + nBase + w*16 + L)*256 + q*8;
  const u16* alp = fal + (bOff + nBase + w*16 + L)*256 + q*8;
  const u16* bhp = fah + (bOff + mBase + L)*256 + q*8;
  const u16* blp = fal + (bOff + mBase + L)*256 + q*8;
  f4v z4={0.f,0.f,0.f,0.f};
  f4v acc[4]={z4,z4,z4,z4};
  for (int k0=0;k0<256;k0+=32){
    s8v ah=*(const s8v*)(ahp+k0), al=*(const s8v*)(alp+k0);
    #pragma unroll
    for (int t=0;t<4;t++){
      s8v bh=*(const s8v*)(bhp + (size_t)t*16*256 + k0);
      s8v bl=*(const s8v*)(blp + (size_t)t*16*256 + k0);
      acc[t]=MFMA(ah,bh,acc[t]);
      acc[t]=MFMA(ah,bl,acc[t]);
      acc[t]=MFMA(al,bh,acc[t]);
    }
  }
  #pragma unroll
  for (int t=0;t<4;t++)
    #pragma unroll
    for (int reg=0;reg<4;reg++)
      sg[w*16 + q*4 + reg][t*16 + L] = acc[t][reg] > 0.f;
  __syncthreads();
  if (tid<128){
    int row=tid>>1, ww=tid&1;
    int nG = nBase+row;
    u32 word=0;
    if (sel8[b*NN + nG]){
      for (int j=0;j<32;j++){
        int m = mBase + ww*32 + j;
        if (sg[row][ww*32+j] && sel8[b*NN+m]) word |= (1u<<j);
      }
    }
    conn[((size_t)b*NN + nG)*32 + (mBase>>5) + ww] = word;
  }
}

// ---------- s1/s2 ----------
template<typename VT>
__global__ __launch_bounds__(256) void k_s1s2(const VT* __restrict__ V, int ldV, int colStep,
    const float* __restrict__ a1, const float* __restrict__ a2, int aStep,
    float* __restrict__ s1a, float* __restrict__ s2a){
  int h = blockIdx.y;
  int r = blockIdx.x*4 + (threadIdx.x>>6);
  int lane = threadIdx.x&63;
  float4 v;
  if constexpr (sizeof(VT)==2) v = ld4bf((const u16*)V + (size_t)r*ldV + h*colStep + lane*4);
  else                         v = *(const float4*)((const float*)V + (size_t)r*ldV + h*colStep + lane*4);
  const float* a1p = a1 + h*aStep; const float* a2p = a2 + h*aStep;
  float4 w1 = *(const float4*)(a1p+lane*4), w2 = *(const float4*)(a2p+lane*4);
  float d1 = v.x*w1.x+v.y*w1.y+v.z*w1.z+v.w*w1.w;
  float d2 = v.x*w2.x+v.y*w2.y+v.z*w2.z+v.w*w2.w;
  d1=wredsum(d1); d2=wredsum(d2);
  if (lane==0){ s1a[h*BN+r]=d1; s2a[h*BN+r]=d2; }
}

// ---------- row max of s2 over connected m ----------
__global__ __launch_bounds__(256) void k_rowmax(const float* __restrict__ s2a,
    const u32* __restrict__ conn, float* __restrict__ M2a){
  int h = blockIdx.y;
  int r = blockIdx.x*4 + (threadIdx.x>>6);
  int lane = threadIdx.x&63;
  int b = r>>10;
  const float* s2p = s2a + h*BN + b*NN;
  float mx = -3.0e38f;
  #pragma unroll
  for (int t=0;t<16;t++){
    int m = lane + t*64;
    u32 wd = conn[(size_t)r*32 + (m>>5)];
    if ((wd>>(m&31))&1u) mx = fmaxf(mx, s2p[m]);
  }
  mx = wredmax(mx);
  if (lane==0) M2a[h*BN+r] = mx;
}

// ---------- MFMA GAT attention v3: pipelined, col-tiled ----------
// grid (256/(NT*16), 128, heads); one barrier per 32-K chunk; V prefetched.
template<typename VT, int NT>
__global__ __launch_bounds__(256) void k_mattn2(const float* __restrict__ s1a, const float* __restrict__ s2a,
    const float* __restrict__ M2a, const u32* __restrict__ conn,
    const VT* __restrict__ V, int vStride, int headMul, u16* __restrict__ Out, int oStride){
  __shared__ __align__(16) u16 Vt[2][NT*16][40];
  const int NL = NT*2;
  int tid=threadIdx.x, w=tid>>6, lane=tid&63, L=lane&15, q=lane>>4;
  int colBase = blockIdx.x*(NT*16);
  int rowBase = blockIdx.y*64;
  int h = blockIdx.z;
  int hOff = h*headMul, sOff = h*BN;
  int b = rowBase>>10;
  size_t bOff = (size_t)b*NN;
  int r = rowBase + w*16 + L;
  float s1v = s1a[sOff+r];
  float rmv = leakyf(s1v + M2a[sOff+r]);
  const float* s2p = s2a + sOff + bOff;
  f4v z4={0.f,0.f,0.f,0.f};
  f4v acc[NT];
  #pragma unroll
  for (int t=0;t<NT;t++) acc[t]=z4;
  float sumP = 0.f;
  int sm_ = tid&31, sd0 = (tid>>5)*NL;
  u16 pre[NL];
  float fpre[NL];
  {  // prologue: chunk 0 -> LDS[0]
    const VT* vp = V + (bOff + sm_)*(size_t)vStride + hOff + colBase + sd0;
    if constexpr (sizeof(VT)==2){
      #pragma unroll
      for (int g2=0;g2<NL/8;g2++) *(uint4*)&pre[g2*8] = *(const uint4*)((const u16*)vp + g2*8);
    } else {
      #pragma unroll
      for (int g2=0;g2<NL/8;g2++) load8((const float*)vp + g2*8, &fpre[g2*8]);
      #pragma unroll
      for (int i=0;i<NL;i++) pre[i]=f2b(fpre[i]);
    }
    #pragma unroll
    for (int i=0;i<NL;i++) Vt[0][sd0+i][sm_] = pre[i];
  }
  for (int k0=0;k0<NN;k0+=32){
    int cur=(k0>>5)&1;
    bool have = (k0+32)<NN;
    if (have){  // issue next chunk's loads before P-build (latency hidden)
      const VT* vp = V + (bOff + k0+32 + sm_)*(size_t)vStride + hOff + colBase + sd0;
      if constexpr (sizeof(VT)==2){
        #pragma unroll
        for (int g2=0;g2<NL/8;g2++) *(uint4*)&pre[g2*8] = *(const uint4*)((const u16*)vp + g2*8);
      } else {
        #pragma unroll
        for (int g2=0;g2<NL/8;g2++) load8((const float*)vp + g2*8, &fpre[g2*8]);
      }
    }
    u32 cw = conn[(size_t)r*32 + (k0>>5)];
    s8v pf;
    #pragma unroll
    for (int j=0;j<8;j++){
      int m = k0 + q*8 + j;
      float ev = ((cw>>(q*8+j))&1u) ? leakyf(s1v + s2p[m]) : -9.0e15f;
      float p = exp0(ev - rmv);
      sumP += p;
      pf[j] = (short)f2b(p);
    }
    __syncthreads();   // LDS[cur] writes (prev iter) visible; LDS[cur^1] free
    if (have){
      if constexpr (sizeof(VT)!=2){
        #pragma unroll
        for (int i=0;i<NL;i++) pre[i]=f2b(fpre[i]);
      }
      #pragma unroll
      for (int i=0;i<NL;i++) Vt[cur^1][sd0+i][sm_] = pre[i];
    }
    #pragma unroll
    for (int t=0;t<NT;t++){
      s8v vf = *(const s8v*)&Vt[cur][t*16+L][q*8];
      acc[t] = MFMA(pf, vf, acc[t]);
    }
  }
  sumP += __shfl_xor(sumP,16);
  sumP += __shfl_xor(sumP,32);
  float rsi[4];
  #pragma unroll
  for (int reg=0;reg<4;reg++) rsi[reg] = 1.f / __shfl(sumP, q*4+reg);
  #pragma unroll
  for (int t=0;t<NT;t++){
    int col = hOff + colBase + t*16 + L;
    #pragma unroll
    for (int reg=0;reg<4;reg++){
      int row = rowBase + w*16 + q*4 + reg;
      Out[(size_t)row*oStride + col] = f2b(eluf(acc[t][reg]*rsi[reg]));
    }
  }
}

// ---------- LayerNorms ----------
__global__ __launch_bounds__(256) void k_ln_x(const float* __restrict__ x, const float* __restrict__ g,
                                              const float* __restrict__ bb, u16* __restrict__ out){
  int r = blockIdx.x*4 + (threadIdx.x>>6);
  int lane=threadIdx.x&63;
  float4 v = *(const float4*)(x + (size_t)r*DD + lane*4);
  float s = v.x+v.y+v.z+v.w;
  float s2 = v.x*v.x+v.y*v.y+v.z*v.z+v.w*v.w;
  s = wredsum(s); s2 = wredsum(s2);
  float mean = s*(1.f/256.f);
  float var = s2*(1.f/256.f) - mean*mean;
  float rstd = rsqrtf(var + 1e-5f);
  float4 gv = *(const float4*)(g+lane*4), bv = *(const float4*)(bb+lane*4);
  u16 t[4];
  t[0]=f2b((v.x-mean)*rstd*gv.x+bv.x); t[1]=f2b((v.y-mean)*rstd*gv.y+bv.y);
  t[2]=f2b((v.z-mean)*rstd*gv.z+bv.z); t[3]=f2b((v.w-mean)*rstd*gv.w+bv.w);
  *(uint2*)(out + (size_t)r*DD + lane*4) = *(uint2*)&t[0];
}

__global__ __launch_bounds__(256) void k_ln_kv(const u16* __restrict__ gout, const float* __restrict__ pe,
    const u8* __restrict__ sel8, const float* __restrict__ g, const float* __restrict__ bb,
    u16* __restrict__ out){
  int r = blockIdx.x*4 + (threadIdx.x>>6);
  int lane=threadIdx.x&63;
  int n = r & 1023;
  float4 v = make_float4(0.f,0.f,0.f,0.f);
  if (sel8[r]){
    float4 gv = ld4bf(gout + (size_t)r*DD + lane*4);
    float4 pv = *(const float4*)(pe + (size_t)n*DD + lane*4);
    v = make_float4(gv.x+pv.x, gv.y+pv.y, gv.z+pv.z, gv.w+pv.w);
  }
  float s = v.x+v.y+v.z+v.w;
  float s2 = v.x*v.x+v.y*v.y+v.z*v.z+v.w*v.w;
  s = wredsum(s); s2 = wredsum(s2);
  float mean = s*(1.f/256.f);
  float var = s2*(1.f/256.f) - mean*mean;
  float rstd = rsqrtf(var + 1e-5f);
  float4 gv = *(const float4*)(g+lane*4), bv = *(const float4*)(bb+lane*4);
  u16 t[4];
  t[0]=f2b((v.x-mean)*rstd*gv.x+bv.x); t[1]=f2b((v.y-mean)*rstd*gv.y+bv.y);
  t[2]=f2b((v.z-mean)*rstd*gv.z+bv.z); t[3]=f2b((v.w-mean)*rstd*gv.w+bv.w);
  *(uint2*)(out + (size_t)r*DD + lane*4) = *(uint2*)&t[0];
}

// ---------- CA max pass (exp-free) ----------
__global__ __launch_bounds__(256) void k_mca_max(const u16* __restrict__ q, const u16* __restrict__ k,
    const u8* __restrict__ sel8, float* __restrict__ cmax){
  __shared__ __align__(16) u16 Qls[64][72];
  __shared__ __align__(16) u16 Kls[64][72];
  __shared__ float cw4[4];
  int tid=threadIdx.x;
  int w = tid>>6, lane = tid&63, L = lane&15, qd = lane>>4;
  int b=blockIdx.z, h=blockIdx.y, rowBase=blockIdx.x*64;
  size_t bOff = (size_t)b*NN;
  {
    float c = 0.f;
    #pragma unroll
    for (int i=0;i<4;i++) c += sel8[b*NN + tid*4 + i] ? 0.f : 1.f;
    c = wredsum(c);
    if (lane==0) cw4[w]=c;
  }
  {
    int r=tid>>2, c0=(tid&3)*16;
    size_t base = (bOff + rowBase + r)*(size_t)DD + h*64 + c0;
    *(uint4*)&Qls[r][c0]   = *(const uint4*)(q + base);
    *(uint4*)&Qls[r][c0+8] = *(const uint4*)(q + base + 8);
  }
  float um[4];
  #pragma unroll
  for (int i=0;i<4;i++) um[i]=-3.0e38f;
  for (int m0=0;m0<NN;m0+=64){
    __syncthreads();
    {
      int r=tid>>2, c0=(tid&3)*16;
      size_t base = (bOff + m0 + r)*(size_t)DD + h*64 + c0;
      *(uint4*)&Kls[r][c0]   = *(const uint4*)(k + base);
      *(uint4*)&Kls[r][c0+8] = *(const uint4*)(k + base + 8);
    }
    __syncthreads();
    f4v zero = {0.f,0.f,0.f,0.f};
    f4v sa[4] = {zero,zero,zero,zero};
    #pragma unroll
    for (int kc=0;kc<64;kc+=32){
      s8v af = *(const s8v*)&Qls[w*16 + L][kc + qd*8];
      #pragma unroll
      for (int t=0;t<4;t++){
        s8v bfr = *(const s8v*)&Kls[t*16 + L][kc + qd*8];
        sa[t] = MFMA(af, bfr, sa[t]);
      }
    }
    #pragma unroll
    for (int t=0;t<4;t++){
      int m = m0 + t*16 + L;
      if (sel8[b*NN+m]){
        #pragma unroll
        for (int reg=0;reg<4;reg++) um[reg] = fmaxf(um[reg], sa[t][reg]*0.125f);
      }
    }
  }
  #pragma unroll
  for (int off=1;off<16;off<<=1)
    #pragma unroll
    for (int reg=0;reg<4;reg++) um[reg] = fmaxf(um[reg], __shfl_xor(um[reg],off));
  __syncthreads();
  float cn = cw4[0]+cw4[1]+cw4[2]+cw4[3];
  if (L==0){
    #pragma unroll
    for (int reg=0;reg<4;reg++){
      int row = rowBase + w*16 + qd*4 + reg;
      float M = um[reg];
      if (cn>0.f) M = fmaxf(M, -1.0e9f);
      cmax[((size_t)b*HC+h)*NN + row] = M;
    }
  }
}

// ---------- CA attention (epilogue-normalized) ----------
__global__ __launch_bounds__(256) void k_mca_av(const u16* __restrict__ q, const u16* __restrict__ k,
    const u16* __restrict__ v, const u8* __restrict__ sel8,
    const float* __restrict__ cmax, u16* __restrict__ O){
  __shared__ __align__(16) u16 Qls[64][72];
  __shared__ __align__(16) u16 KP[64][72];
  __shared__ __align__(16) u16 Vt[64][72];
  int tid=threadIdx.x;
  int w = tid>>6, lane = tid&63, L = lane&15, qd = lane>>4;
  int b=blockIdx.z, h=blockIdx.y, rowBase=blockIdx.x*64;
  size_t bOff = (size_t)b*NN;
  {
    int r=tid>>2, c0=(tid&3)*16;
    size_t base = (bOff + rowBase + r)*(size_t)DD + h*64 + c0;
    *(uint4*)&Qls[r][c0]   = *(const uint4*)(q + base);
    *(uint4*)&Qls[r][c0+8] = *(const uint4*)(q + base + 8);
  }
  float rm[4], sp[4];
  #pragma unroll
  for (int reg=0;reg<4;reg++){
    rm[reg]=cmax[((size_t)b*HC+h)*NN + rowBase + w*16 + qd*4 + reg];
    sp[reg]=0.f;
  }
  f4v zero = {0.f,0.f,0.f,0.f};
  f4v acc[4] = {zero,zero,zero,zero};
  int svm = tid&63, svd0 = (tid>>6)*16;
  for (int m0=0;m0<NN;m0+=64){
    __syncthreads();
    {
      int r=tid>>2, c0=(tid&3)*16;
      size_t base = (bOff + m0 + r)*(size_t)DD + h*64 + c0;
      *(uint4*)&KP[r][c0]   = *(const uint4*)(k + base);
      *(uint4*)&KP[r][c0+8] = *(const uint4*)(k + base + 8);
      size_t vb_ = (bOff + m0 + svm)*(size_t)DD + h*64 + svd0;
      uint4 u0 = *(const uint4*)(v + vb_);
      uint4 u1 = *(const uint4*)(v + vb_ + 8);
      u16 tmp[16];
      *(uint4*)&tmp[0]=u0; *(uint4*)&tmp[8]=u1;
      #pragma unroll
      for (int i=0;i<16;i++) Vt[svd0+i][svm] = tmp[i];
    }
    __syncthreads();
    f4v sa[4] = {zero,zero,zero,zero};
    #pragma unroll
    for (int kc=0;kc<64;kc+=32){
      s8v af = *(const s8v*)&Qls[w*16 + L][kc + qd*8];
      #pragma unroll
      for (int t=0;t<4;t++){
        s8v bfr = *(const s8v*)&KP[t*16 + L][kc + qd*8];
        sa[t] = MFMA(af, bfr, sa[t]);
      }
    }
    __syncthreads();
    #pragma unroll
    for (int t=0;t<4;t++){
      int m = m0 + t*16 + L;
      bool sl = sel8[b*NN+m];
      #pragma unroll
      for (int reg=0;reg<4;reg++){
        float val = sl ? sa[t][reg]*0.125f : -1.0e9f;
        float pv = exp0(val - rm[reg]);
        sp[reg] += pv;
        KP[w*16 + qd*4 + reg][t*16 + L] = f2b(pv);
      }
    }
    __syncthreads();
    #pragma unroll
    for (int mc=0;mc<64;mc+=32){
      s8v pf = *(const s8v*)&KP[w*16 + L][mc + qd*8];
      #pragma unroll
      for (int t=0;t<4;t++){
        s8v vf = *(const s8v*)&Vt[t*16 + L][mc + qd*8];
        acc[t] = MFMA(pf, vf, acc[t]);
      }
    }
  }
  #pragma unroll
  for (int off=1;off<16;off<<=1)
    #pragma unroll
    for (int reg=0;reg<4;reg++) sp[reg] += __shfl_xor(sp[reg],off);
  float ri[4];
  #pragma unroll
  for (int reg=0;reg<4;reg++) ri[reg] = 1.f/sp[reg];
  #pragma unroll
  for (int t=0;t<4;t++){
    int col = h*64 + t*16 + L;
    #pragma unroll
    for (int reg=0;reg<4;reg++){
      int row = rowBase + w*16 + qd*4 + reg;
      O[(bOff + row)*(size_t)DD + col] = f2b(acc[t][reg]*ri[reg]);
    }
  }
}

extern "C" void kernel_launch(void* const* d_in, const int* in_sizes, int n_in,
                              void* d_out, int out_size, void* d_ws, size_t ws_size,
                              hipStream_t stream) {
  (void)in_sizes; (void)n_in; (void)out_size;
  const float* x      = (const float*)d_in[0];
  const int*   mask   = (const int*  )d_in[1];
  const float* pe     = (const float*)d_in[2];
  const float* sim_Wx = (const float*)d_in[3];
  const float* sim_Wq = (const float*)d_in[4];
  const float* adj_W  = (const float*)d_in[5];
  const float* gat_W  = (const float*)d_in[6];
  const float* gat_a1 = (const float*)d_in[7];
  const float* gat_a2 = (const float*)d_in[8];
  const float* gat_Wo = (const float*)d_in[9];
  const float* gat_ao1= (const float*)d_in[10];
  const float* gat_ao2= (const float*)d_in[11];
  const float* ln3_g  = (const float*)d_in[12];
  const float* ln3_b  = (const float*)d_in[13];
  const float* ln4_g  = (const float*)d_in[14];
  const float* ln4_b  = (const float*)d_in[15];
  const float* ca_Wq  = (const float*)d_in[16];
  const float* ca_Wk  = (const float*)d_in[17];
  const float* ca_Wv  = (const float*)d_in[18];
  const float* ca_Wp  = (const float*)d_in[19];
  const float* gamma  = (const float*)d_in[20];
  float* out    = (float*)d_out;
  float* simOut = out + (size_t)BN*DD;

  const size_t MB = 1024*1024;
  bool big = ws_size >= 98*MB;
  char* W = (char*)d_ws;
  float* pq   = (float*)W;
  float* cnt  = pq + 2048;
  float* sq   = cnt + 16;
  float* s1a  = (float*)(W + 64*1024);
  float* s2a  = (float*)(W + 320*1024);
  float* M2a  = (float*)(W + 576*1024);
  float* cam  = (float*)(W + 1088*1024);
  u8*    sel8 = (u8*)(W + 1400*1024);
  u32*   conn = (u32*)(W + 2*MB);
  u16*   WT0  = (u16*)(W + 3*MB);
  u16*   WoT  = (u16*)(W + 4*MB);
  u16*   WQT  = (u16*)(W + 5*MB);
  u16*   WKT  = WQT + 65536;
  u16*   WVT  = WKT + 65536;
  u16*   WPT  = WVT + 65536;
  u16*   sWxh = (u16*)(W + 5*MB + 512*1024);
  u16*   sWxl = sWxh + 65536;
  u16*   aWh  = sWxl + 65536;
  u16*   aWl  = aWh + 65536;
  u16*   xh   = (u16*)(W + 6*MB);
  u16*   xl   = (u16*)(W + 10*MB);
  float* S0   = (float*)(W + 14*MB);
  u16*   fah  = (u16*)(W + 22*MB);
  u16*   fal  = (u16*)(W + 26*MB);
  u16*   T2   = (u16*)(W + 30*MB);

  // prep
  k_split<<<BN*DD/2048,256,0,stream>>>(x, xh, xl);
  k_transpose<<<dim3(4,4,HG),256,0,stream>>>(gat_W, WT0, 256, 65536);
  k_transpose<<<dim3(4,32,1),256,0,stream>>>(gat_Wo, WoT, 2048, 0);
  k_transpose4<<<dim3(4,4,4),256,0,stream>>>(ca_Wq, ca_Wk, ca_Wv, ca_Wp, WQT);
  k_transp_split<<<dim3(4,4,1),256,0,stream>>>(sim_Wx, sWxh, sWxl);
  k_transp_split<<<dim3(4,4,1),256,0,stream>>>(adj_W, aWh, aWl);

  hipMemsetAsync(pq, 0, (2048+16)*sizeof(float), stream);
  k_posq<<<dim3(BB,16),256,0,stream>>>(x, mask, pq, cnt);
  k_sq<<<BB,256,0,stream>>>(pq, cnt, sim_Wq, sq);
  k_msgemm<0><<<dim3(4,128),256,0,stream>>>(xh, xl, sWxh, sWxl, S0, nullptr, nullptr);  // y
  k_simsel<<<BN/4,256,0,stream>>>(S0, sq, simOut, sel8);
  k_msgemm<4><<<dim3(4,128),256,0,stream>>>(xh, xl, aWh, aWl, nullptr, fah, fal);       // fa split
  k_mconnect<<<dim3(16,16,BB),256,0,stream>>>(fah, fal, sel8, conn);

  if (big){
    u16* whcat = (u16*)(W + 34*MB);
    u16* htcat = (u16*)(W + 66*MB);
    u16* qx = (u16*)(W + 34*MB);
    u16* kv = (u16*)(W + 38*MB);
    u16* qb = (u16*)(W + 42*MB);
    u16* vb = (u16*)(W + 50*MB);
    u16* Ob = (u16*)(W + 54*MB);

    k_mgemm<3><<<dim3(32,128),256,0,stream>>>(xh, WT0, 256, 256, nullptr, nullptr, nullptr, whcat); // Wh_cat
    k_s1s2<u16><<<dim3(BN/4,HG),256,0,stream>>>(whcat, 2048, 256, gat_a1, gat_a2, 256, s1a, s2a);
    k_rowmax<<<dim3(BN/4,HG),256,0,stream>>>(s2a, conn, M2a);
    k_mattn2<u16,16><<<dim3(1,128,HG),256,0,stream>>>(s1a, s2a, M2a, conn, whcat, 2048, 256, htcat, 2048);
    k_mgemm<0><<<dim3(4,128),256,0,stream>>>(htcat, WoT, 2048, 2048, S0, nullptr, nullptr, nullptr); // Who fp32
    k_s1s2<float><<<dim3(BN/4,1),256,0,stream>>>(S0, 256, 0, gat_ao1, gat_ao2, 0, s1a, s2a);
    k_rowmax<<<dim3(BN/4,1),256,0,stream>>>(s2a, conn, M2a);
    k_mattn2<float,8><<<dim3(2,128,1),256,0,stream>>>(s1a, s2a, M2a, conn, S0, 256, 0, T2, 256);  // gout

    k_ln_x<<<BN/4,256,0,stream>>>(x, ln3_g, ln3_b, qx);
    k_ln_kv<<<BN/4,256,0,stream>>>(T2, pe, sel8, ln4_g, ln4_b, kv);
    k_mgemm3<<<dim3(4,128,3),256,0,stream>>>(qx, kv, WQT, qb);     // qb,kb,vb (stride 4MB)
    k_mca_max<<<dim3(16,HC,BB),256,0,stream>>>(qb, qb + 2097152, sel8, cam);
    k_mca_av<<<dim3(16,HC,BB),256,0,stream>>>(qb, qb + 2097152, vb, sel8, cam, Ob);
    k_mgemm<2><<<dim3(4,128),256,0,stream>>>(Ob, WPT, 256, 256, out, x, gamma, nullptr);
  } else {
    u16* T0 = fah;
    u16* T1 = fal;
    u16* S0b = (u16*)S0;
    hipMemsetAsync(S0, 0, 8*MB, stream);
    for (int h=0;h<HG;h++){
      k_mgemm<3><<<dim3(4,128),256,0,stream>>>(xh, WT0 + (size_t)h*65536, 256, 256, nullptr, nullptr, nullptr, T0);
      k_s1s2<u16><<<dim3(BN/4,1),256,0,stream>>>(T0, 256, 0, gat_a1 + h*DD, gat_a2 + h*DD, 0, s1a, s2a);
      k_rowmax<<<dim3(BN/4,1),256,0,stream>>>(s2a, conn, M2a);
      k_mattn2<u16,8><<<dim3(2,128,1),256,0,stream>>>(s1a, s2a, M2a, conn, T0, 256, 0, T1, 256);
      k_mgemm<1><<<dim3(4,128),256,0,stream>>>(T1, WoT + (size_t)h*256, 256, 2048, S0, nullptr, nullptr, nullptr);
    }
    k_s1s2<float><<<dim3(BN/4,1),256,0,stream>>>(S0, 256, 0, gat_ao1, gat_ao2, 0, s1a, s2a);
    k_rowmax<<<dim3(BN/4,1),256,0,stream>>>(s2a, conn, M2a);
    k_mattn2<float,8><<<dim3(2,128,1),256,0,stream>>>(s1a, s2a, M2a, conn, S0, 256, 0, T2, 256); // gout

    k_ln_x<<<BN/4,256,0,stream>>>(x, ln3_g, ln3_b, T1);
    k_ln_kv<<<BN/4,256,0,stream>>>(T2, pe, sel8, ln4_g, ln4_b, T0);
    k_mgemm<3><<<dim3(4,128),256,0,stream>>>(T1, WQT, 256, 256, nullptr, nullptr, nullptr, T2);
    k_mgemm<3><<<dim3(4,128),256,0,stream>>>(T0, WKT, 256, 256, nullptr, nullptr, nullptr, T1);
    k_mgemm<3><<<dim3(4,128),256,0,stream>>>(T0, WVT, 256, 256, nullptr, nullptr, nullptr, S0b);
    k_mca_max<<<dim3(16,HC,BB),256,0,stream>>>(T2, T1, sel8, cam);
    k_mca_av<<<dim3(16,HC,BB),256,0,stream>>>(T2, T1, S0b, sel8, cam, T0);
    k_mgemm<2><<<dim3(4,128),256,0,stream>>>(T0, WPT, 256, 256, out, x, gamma, nullptr);
  }
}